// Round 1
// baseline (888.884 us; speedup 1.0000x reference)
//
#include <hip/hip_runtime.h>

#define S 8192
#define D 1024
#define WINDOW 128
#define TQ 16
#define UMAX 288   // padded union window size (max real = 271)
#define BK 32
#define PAD 68     // LDS row stride (floats): mult of 4 for b128, odd bank group

__device__ __forceinline__ float wave_sum(float v) {
  #pragma unroll
  for (int off = 32; off > 0; off >>= 1) v += __shfl_xor(v, off, 64);
  return v;
}
__device__ __forceinline__ float wave_max(float v) {
  #pragma unroll
  for (int off = 32; off > 0; off >>= 1) v = fmaxf(v, __shfl_xor(v, off, 64));
  return v;
}

// ---------------------------------------------------------------------------
// q = x*Wq^T + bq ; k = x*Wk^T + bk   (both [S,D], fp32)
// 64x64 tile per block, BK=32, shared x tile serves both outputs.
// ---------------------------------------------------------------------------
__global__ __launch_bounds__(256) void proj_kernel(
    const float* __restrict__ x, const float* __restrict__ Wq,
    const float* __restrict__ bqv, const float* __restrict__ Wk,
    const float* __restrict__ bkv, float* __restrict__ qout,
    float* __restrict__ kout)
{
  __shared__ __align__(16) float xs[BK][PAD];   // [kk][row]
  __shared__ __align__(16) float wqs[BK][PAD];
  __shared__ __align__(16) float wks[BK][PAD];

  const int tid = threadIdx.x;
  const int tx = tid & 15;
  const int ty = tid >> 4;
  const int t0 = blockIdx.x * 64;
  const int i0 = blockIdx.y * 64;

  float accq[4][4] = {};
  float acck[4][4] = {};

  const int lrow0 = tid >> 3;       // 0..31
  const int lc4   = (tid & 7) * 4;  // 0..28

  for (int k0 = 0; k0 < D; k0 += BK) {
    __syncthreads();
    #pragma unroll
    for (int p = 0; p < 2; ++p) {
      int row = lrow0 + p * 32;
      float4 a = *(const float4*)(x  + (size_t)(t0 + row) * D + k0 + lc4);
      float4 b = *(const float4*)(Wq + (size_t)(i0 + row) * D + k0 + lc4);
      float4 c = *(const float4*)(Wk + (size_t)(i0 + row) * D + k0 + lc4);
      xs [lc4+0][row]=a.x; xs [lc4+1][row]=a.y; xs [lc4+2][row]=a.z; xs [lc4+3][row]=a.w;
      wqs[lc4+0][row]=b.x; wqs[lc4+1][row]=b.y; wqs[lc4+2][row]=b.z; wqs[lc4+3][row]=b.w;
      wks[lc4+0][row]=c.x; wks[lc4+1][row]=c.y; wks[lc4+2][row]=c.z; wks[lc4+3][row]=c.w;
    }
    __syncthreads();
    #pragma unroll
    for (int kk = 0; kk < BK; ++kk) {
      float4 av = *(const float4*)&xs [kk][ty*4];
      float4 bv = *(const float4*)&wqs[kk][tx*4];
      float4 cv = *(const float4*)&wks[kk][tx*4];
      float a[4] = {av.x, av.y, av.z, av.w};
      float b[4] = {bv.x, bv.y, bv.z, bv.w};
      float c[4] = {cv.x, cv.y, cv.z, cv.w};
      #pragma unroll
      for (int r = 0; r < 4; ++r)
        #pragma unroll
        for (int cc = 0; cc < 4; ++cc) {
          accq[r][cc] = fmaf(a[r], b[cc], accq[r][cc]);
          acck[r][cc] = fmaf(a[r], c[cc], acck[r][cc]);
        }
    }
  }

  float4 bq4 = *(const float4*)(bqv + i0 + tx*4);
  float4 bk4 = *(const float4*)(bkv + i0 + tx*4);
  #pragma unroll
  for (int r = 0; r < 4; ++r) {
    int trow = t0 + ty*4 + r;
    float4 oq = { accq[r][0]+bq4.x, accq[r][1]+bq4.y, accq[r][2]+bq4.z, accq[r][3]+bq4.w };
    float4 ok = { acck[r][0]+bk4.x, acck[r][1]+bk4.y, acck[r][2]+bk4.z, acck[r][3]+bk4.w };
    *(float4*)(qout + (size_t)trow * D + i0 + tx*4) = oq;
    *(float4*)(kout + (size_t)trow * D + i0 + tx*4) = ok;
  }
}

// ---------------------------------------------------------------------------
// xsum[d] = sum_t x[t][d]
// ---------------------------------------------------------------------------
__global__ __launch_bounds__(256) void colsum_kernel(const float* __restrict__ x,
                                                     float* __restrict__ xsum)
{
  int d = blockIdx.x * 256 + threadIdx.x;
  int tbase = blockIdx.y * 256;
  float s = 0.f;
  for (int t = 0; t < 256; ++t) s += x[(size_t)(tbase + t) * D + d];
  atomicAdd(&xsum[d], s);
}

// ---------------------------------------------------------------------------
// Windowed attention: 16 query rows per block.
//   out_t = ( sum_{s in win} (e^{sc-m} - e^{-m}) x_s + e^{-m} * xsum ) / denom
//   denom = sum_{win} e^{sc-m} + (S - cnt) e^{-m},  m = max(0, max_win sc)
// ---------------------------------------------------------------------------
__global__ __launch_bounds__(256) void attn_kernel(
    const float* __restrict__ x, const float* __restrict__ q,
    const float* __restrict__ kmat, const float* __restrict__ xsum,
    float* __restrict__ out)
{
  __shared__ __align__(16) float sc[TQ][UMAX];
  __shared__ float e0s[TQ], dinv[TQ];

  const int tid  = threadIdx.x;
  const int lane = tid & 63;
  const int wv   = tid >> 6;            // wave id 0..3
  const int t0   = blockIdx.x * TQ;
  const int lo_u = max(0, t0 - WINDOW);
  const int hi_u = min(S, t0 + TQ - 1 + WINDOW);
  const int ucnt = hi_u - lo_u;

  // phase 0: zero weights
  for (int i = tid; i < TQ * UMAX; i += 256) (&sc[0][0])[i] = 0.f;
  __syncthreads();

  // phase 1: scores. wave wv handles ti = 4wv..4wv+3 (4 q-rows held in regs)
  {
    const int tiB = wv * 4;
    float4 qf[4][4];
    #pragma unroll
    for (int g = 0; g < 4; ++g) {
      int t = t0 + tiB + g;
      #pragma unroll
      for (int j = 0; j < 4; ++j)
        qf[g][j] = *(const float4*)(q + (size_t)t * D + lane*4 + j*256);
    }
    const int wlo = max(0, t0 + tiB - WINDOW);
    const int whi = min(S, t0 + tiB + 3 + WINDOW);
    for (int s = wlo; s < whi; ++s) {
      float4 kf[4];
      #pragma unroll
      for (int j = 0; j < 4; ++j)
        kf[j] = *(const float4*)(kmat + (size_t)s * D + lane*4 + j*256);
      float acc[4];
      #pragma unroll
      for (int g = 0; g < 4; ++g) {
        float v = 0.f;
        #pragma unroll
        for (int j = 0; j < 4; ++j) {
          v = fmaf(qf[g][j].x, kf[j].x, v);
          v = fmaf(qf[g][j].y, kf[j].y, v);
          v = fmaf(qf[g][j].z, kf[j].z, v);
          v = fmaf(qf[g][j].w, kf[j].w, v);
        }
        acc[g] = v;
      }
      #pragma unroll
      for (int g = 0; g < 4; ++g) {
        float tot = wave_sum(acc[g]);
        int t = t0 + tiB + g;
        if (lane == 0 && s >= t - WINDOW && s < t + WINDOW)
          sc[tiB + g][s - lo_u] = tot;
      }
    }
  }
  __syncthreads();

  // phase 2: softmax with zero-entry correction
  #pragma unroll
  for (int g = 0; g < 4; ++g) {
    int ti = wv * 4 + g;
    int t = t0 + ti;
    int lo = max(0, t - WINDOW), hi = min(S, t + WINDOW);
    int cnt = hi - lo, off = lo - lo_u;
    float m = 0.f;                               // zeros present in every row
    for (int i = lane; i < cnt; i += 64) m = fmaxf(m, sc[ti][off + i]);
    m = wave_max(m);
    float e0 = __expf(-m);
    float ssum = 0.f;
    for (int i = lane; i < cnt; i += 64) {
      float e = __expf(sc[ti][off + i] - m);
      ssum += e;
      sc[ti][off + i] = e - e0;
    }
    ssum = wave_sum(ssum);
    if (lane == 0) {
      float denom = ssum + (float)(S - cnt) * e0;
      dinv[ti] = 1.f / denom;
      e0s[ti]  = e0;
    }
  }
  __syncthreads();

  // phase 3: PV over union window; each thread owns one float4 column group
  {
    const int c4 = tid * 4;
    float4 acc[TQ];
    #pragma unroll
    for (int ti = 0; ti < TQ; ++ti) acc[ti] = make_float4(0.f, 0.f, 0.f, 0.f);

    for (int su = 0; su < ucnt; su += 4) {   // over-read ≤3 hits zeroed sc / valid rows
      float4 xr[4];
      #pragma unroll
      for (int u = 0; u < 4; ++u)
        xr[u] = *(const float4*)(x + (size_t)(lo_u + su + u) * D + c4);
      #pragma unroll
      for (int ti = 0; ti < TQ; ++ti) {
        float4 w4 = *(const float4*)&sc[ti][su];
        float wvv[4] = {w4.x, w4.y, w4.z, w4.w};
        #pragma unroll
        for (int u = 0; u < 4; ++u) {
          acc[ti].x = fmaf(wvv[u], xr[u].x, acc[ti].x);
          acc[ti].y = fmaf(wvv[u], xr[u].y, acc[ti].y);
          acc[ti].z = fmaf(wvv[u], xr[u].z, acc[ti].z);
          acc[ti].w = fmaf(wvv[u], xr[u].w, acc[ti].w);
        }
      }
    }

    float4 xsv = *(const float4*)(xsum + c4);
    #pragma unroll
    for (int ti = 0; ti < TQ; ++ti) {
      float e0 = e0s[ti], di = dinv[ti];
      float4 o;
      o.x = (acc[ti].x + e0 * xsv.x) * di;
      o.y = (acc[ti].y + e0 * xsv.y) * di;
      o.z = (acc[ti].z + e0 * xsv.z) * di;
      o.w = (acc[ti].w + e0 * xsv.w) * di;
      *(float4*)(out + (size_t)(t0 + ti) * D + c4) = o;
    }
  }
}

extern "C" void kernel_launch(void* const* d_in, const int* in_sizes, int n_in,
                              void* d_out, int out_size, void* d_ws, size_t ws_size,
                              hipStream_t stream) {
  const float* x  = (const float*)d_in[0];
  const float* Wq = (const float*)d_in[1];
  const float* bq = (const float*)d_in[2];
  const float* Wk = (const float*)d_in[3];
  const float* bk = (const float*)d_in[4];
  float* outp = (float*)d_out;

  float* q    = (float*)d_ws;                    // 32 MB
  float* kbuf = q + (size_t)S * D;               // 32 MB
  float* xsum = kbuf + (size_t)S * D;            // 4 KB

  hipMemsetAsync(xsum, 0, D * sizeof(float), stream);
  proj_kernel<<<dim3(S / 64, D / 64), 256, 0, stream>>>(x, Wq, bq, Wk, bk, q, kbuf);
  colsum_kernel<<<dim3(D / 256, S / 256), 256, 0, stream>>>(x, xsum);
  attn_kernel<<<dim3(S / TQ), 256, 0, stream>>>(x, q, kbuf, xsum, outp);
}

// Round 3
// 603.772 us; speedup vs baseline: 1.4722x; 1.4722x over previous
//
#include <hip/hip_runtime.h>

#define S 8192
#define D 1024
#define WINDOW 128
#define TQ 16
#define UMAX 288   // padded union window size (max real = 271)
#define BK 32      // GEMM K-chunk (bf16 elems)
#define PAD 68     // fp32 fallback LDS stride

typedef __attribute__((ext_vector_type(8))) short short8;      // 8 x bf16 frag
typedef __attribute__((ext_vector_type(4))) float floatx4;     // MFMA acc
typedef __attribute__((ext_vector_type(4))) unsigned short ushort4v;

__device__ __forceinline__ float wave_sum(float v) {
  #pragma unroll
  for (int off = 32; off > 0; off >>= 1) v += __shfl_xor(v, off, 64);
  return v;
}
__device__ __forceinline__ float wave_max(float v) {
  #pragma unroll
  for (int off = 32; off > 0; off >>= 1) v = fmaxf(v, __shfl_xor(v, off, 64));
  return v;
}

__device__ __forceinline__ unsigned int f2bf_rn(float f) {
  unsigned int u = __float_as_uint(f);
  return (u + 0x7fffu + ((u >> 16) & 1u)) >> 16;
}

// ---------------------------------------------------------------------------
// fp32 -> (bf16 hi, bf16 lo) split, 4 elems/thread
// ---------------------------------------------------------------------------
__global__ __launch_bounds__(256) void split_kernel(
    const float* __restrict__ src, unsigned short* __restrict__ hi,
    unsigned short* __restrict__ lo)
{
  int i = (blockIdx.x * 256 + threadIdx.x) * 4;
  float4 v = *(const float4*)(src + i);
  float f[4] = {v.x, v.y, v.z, v.w};
  ushort4v h, l;
  #pragma unroll
  for (int c = 0; c < 4; ++c) {
    unsigned int hb = f2bf_rn(f[c]);
    float hf = __uint_as_float(hb << 16);
    unsigned int lb = f2bf_rn(f[c] - hf);
    h[c] = (unsigned short)hb;
    l[c] = (unsigned short)lb;
  }
  *(ushort4v*)(hi + i) = h;
  *(ushort4v*)(lo + i) = l;
}

// ---------------------------------------------------------------------------
// MFMA projection: out = x*W^T + bias for both (Wq,bq)->q and (Wk,bk)->k.
// blockIdx.z selects output. 128x128 tile, BK=32, hi/lo 3-term bf16 split.
// ---------------------------------------------------------------------------
__global__ __launch_bounds__(256) void gemm_qk(
    const unsigned short* __restrict__ xhi, const unsigned short* __restrict__ xlo,
    const unsigned short* __restrict__ wqhi, const unsigned short* __restrict__ wqlo,
    const unsigned short* __restrict__ wkhi, const unsigned short* __restrict__ wklo,
    const float* __restrict__ bqv, const float* __restrict__ bkv,
    float* __restrict__ qout, float* __restrict__ kout)
{
  __shared__ __align__(16) unsigned short Ah[128 * BK];
  __shared__ __align__(16) unsigned short Al[128 * BK];
  __shared__ __align__(16) unsigned short Bh[128 * BK];
  __shared__ __align__(16) unsigned short Bl[128 * BK];

  const int tid  = threadIdx.x;
  const int lane = tid & 63;
  const int wv   = tid >> 6;
  const int t0   = blockIdx.x * 128;
  const int n0   = blockIdx.y * 128;

  const unsigned short* whi = blockIdx.z ? wkhi : wqhi;
  const unsigned short* wlo = blockIdx.z ? wklo : wqlo;
  const float* bias         = blockIdx.z ? bkv  : bqv;
  float* outp               = blockIdx.z ? kout : qout;

  floatx4 acc[4][4] = {};

  const int m0w  = (wv & 1) * 64;
  const int n0w  = (wv >> 1) * 64;
  const int srow = lane >> 2;        // 0..15 row within segment
  const int scol = (lane & 3) * 8;   // bf16 col offset within BK chunk

  for (int k0 = 0; k0 < D; k0 += BK) {
    __syncthreads();
    #pragma unroll
    for (int sg = 0; sg < 2; ++sg) {
      int seg  = wv * 2 + sg;                       // 0..7, 16 rows each
      int arow = t0 + seg * 16 + srow;
      int brow = n0 + seg * 16 + srow;
      size_t ga = (size_t)arow * D + k0 + scol;
      size_t gb = (size_t)brow * D + k0 + scol;
      __builtin_amdgcn_global_load_lds(
          (const __attribute__((address_space(1))) void*)(xhi + ga),
          (__attribute__((address_space(3))) void*)(&Ah[seg * 512]), 16, 0, 0);
      __builtin_amdgcn_global_load_lds(
          (const __attribute__((address_space(1))) void*)(xlo + ga),
          (__attribute__((address_space(3))) void*)(&Al[seg * 512]), 16, 0, 0);
      __builtin_amdgcn_global_load_lds(
          (const __attribute__((address_space(1))) void*)(whi + gb),
          (__attribute__((address_space(3))) void*)(&Bh[seg * 512]), 16, 0, 0);
      __builtin_amdgcn_global_load_lds(
          (const __attribute__((address_space(1))) void*)(wlo + gb),
          (__attribute__((address_space(3))) void*)(&Bl[seg * 512]), 16, 0, 0);
    }
    __syncthreads();

    short8 ah[4], al[4], bh[4], bl[4];
    #pragma unroll
    for (int t = 0; t < 4; ++t) {
      int ar = (m0w + t * 16 + (lane & 15)) * BK + (lane >> 4) * 8;
      int br = (n0w + t * 16 + (lane & 15)) * BK + (lane >> 4) * 8;
      ah[t] = *(const short8*)&Ah[ar];
      al[t] = *(const short8*)&Al[ar];
      bh[t] = *(const short8*)&Bh[br];
      bl[t] = *(const short8*)&Bl[br];
    }
    #pragma unroll
    for (int mt = 0; mt < 4; ++mt)
      #pragma unroll
      for (int nt = 0; nt < 4; ++nt) {
        acc[mt][nt] = __builtin_amdgcn_mfma_f32_16x16x32_bf16(ah[mt], bh[nt], acc[mt][nt], 0, 0, 0);
        acc[mt][nt] = __builtin_amdgcn_mfma_f32_16x16x32_bf16(ah[mt], bl[nt], acc[mt][nt], 0, 0, 0);
        acc[mt][nt] = __builtin_amdgcn_mfma_f32_16x16x32_bf16(al[mt], bh[nt], acc[mt][nt], 0, 0, 0);
      }
  }

  // epilogue: C row=(lane>>4)*4+reg (t index), col=lane&15 (n index)
  #pragma unroll
  for (int mt = 0; mt < 4; ++mt) {
    #pragma unroll
    for (int nt = 0; nt < 4; ++nt) {
      int n = n0 + n0w + nt * 16 + (lane & 15);
      int m = t0 + m0w + mt * 16 + (lane >> 4) * 4;
      float b = bias[n];
      #pragma unroll
      for (int r = 0; r < 4; ++r)
        outp[(size_t)(m + r) * D + n] = acc[mt][nt][r] + b;
    }
  }
}

// ---------------------------------------------------------------------------
// fp32 fallback projection (round-1 kernel) — used if ws too small
// ---------------------------------------------------------------------------
__global__ __launch_bounds__(256) void proj_kernel(
    const float* __restrict__ x, const float* __restrict__ Wq,
    const float* __restrict__ bqv, const float* __restrict__ Wk,
    const float* __restrict__ bkv, float* __restrict__ qout,
    float* __restrict__ kout)
{
  __shared__ __align__(16) float xs[BK][PAD];
  __shared__ __align__(16) float wqs[BK][PAD];
  __shared__ __align__(16) float wks[BK][PAD];

  const int tid = threadIdx.x;
  const int tx = tid & 15;
  const int ty = tid >> 4;
  const int t0 = blockIdx.x * 64;
  const int i0 = blockIdx.y * 64;

  float accq[4][4] = {};
  float acck[4][4] = {};

  const int lrow0 = tid >> 3;
  const int lc4   = (tid & 7) * 4;

  for (int k0 = 0; k0 < D; k0 += BK) {
    __syncthreads();
    #pragma unroll
    for (int p = 0; p < 2; ++p) {
      int row = lrow0 + p * 32;
      float4 a = *(const float4*)(x  + (size_t)(t0 + row) * D + k0 + lc4);
      float4 b = *(const float4*)(Wq + (size_t)(i0 + row) * D + k0 + lc4);
      float4 c = *(const float4*)(Wk + (size_t)(i0 + row) * D + k0 + lc4);
      xs [lc4+0][row]=a.x; xs [lc4+1][row]=a.y; xs [lc4+2][row]=a.z; xs [lc4+3][row]=a.w;
      wqs[lc4+0][row]=b.x; wqs[lc4+1][row]=b.y; wqs[lc4+2][row]=b.z; wqs[lc4+3][row]=b.w;
      wks[lc4+0][row]=c.x; wks[lc4+1][row]=c.y; wks[lc4+2][row]=c.z; wks[lc4+3][row]=c.w;
    }
    __syncthreads();
    #pragma unroll
    for (int kk = 0; kk < BK; ++kk) {
      float4 av = *(const float4*)&xs [kk][ty*4];
      float4 bv = *(const float4*)&wqs[kk][tx*4];
      float4 cv = *(const float4*)&wks[kk][tx*4];
      float a[4] = {av.x, av.y, av.z, av.w};
      float b[4] = {bv.x, bv.y, bv.z, bv.w};
      float c[4] = {cv.x, cv.y, cv.z, cv.w};
      #pragma unroll
      for (int r = 0; r < 4; ++r)
        #pragma unroll
        for (int cc = 0; cc < 4; ++cc) {
          accq[r][cc] = fmaf(a[r], b[cc], accq[r][cc]);
          acck[r][cc] = fmaf(a[r], c[cc], acck[r][cc]);
        }
    }
  }

  float4 bq4 = *(const float4*)(bqv + i0 + tx*4);
  float4 bk4 = *(const float4*)(bkv + i0 + tx*4);
  #pragma unroll
  for (int r = 0; r < 4; ++r) {
    int trow = t0 + ty*4 + r;
    float4 oq = { accq[r][0]+bq4.x, accq[r][1]+bq4.y, accq[r][2]+bq4.z, accq[r][3]+bq4.w };
    float4 ok = { acck[r][0]+bk4.x, acck[r][1]+bk4.y, acck[r][2]+bk4.z, acck[r][3]+bk4.w };
    *(float4*)(qout + (size_t)trow * D + i0 + tx*4) = oq;
    *(float4*)(kout + (size_t)trow * D + i0 + tx*4) = ok;
  }
}

// ---------------------------------------------------------------------------
// xsum[d] = sum_t x[t][d]
// ---------------------------------------------------------------------------
__global__ __launch_bounds__(256) void colsum_kernel(const float* __restrict__ x,
                                                     float* __restrict__ xsum)
{
  int d = blockIdx.x * 256 + threadIdx.x;
  int tbase = blockIdx.y * 256;
  float s = 0.f;
  for (int t = 0; t < 256; ++t) s += x[(size_t)(tbase + t) * D + d];
  atomicAdd(&xsum[d], s);
}

// ---------------------------------------------------------------------------
// Windowed attention: 16 query rows per block (unchanged this round).
// ---------------------------------------------------------------------------
__global__ __launch_bounds__(256) void attn_kernel(
    const float* __restrict__ x, const float* __restrict__ q,
    const float* __restrict__ kmat, const float* __restrict__ xsum,
    float* __restrict__ out)
{
  __shared__ __align__(16) float sc[TQ][UMAX];
  __shared__ float e0s[TQ], dinv[TQ];

  const int tid  = threadIdx.x;
  const int lane = tid & 63;
  const int wv   = tid >> 6;
  const int t0   = blockIdx.x * TQ;
  const int lo_u = max(0, t0 - WINDOW);
  const int hi_u = min(S, t0 + TQ - 1 + WINDOW);
  const int ucnt = hi_u - lo_u;

  for (int i = tid; i < TQ * UMAX; i += 256) (&sc[0][0])[i] = 0.f;
  __syncthreads();

  {
    const int tiB = wv * 4;
    float4 qf[4][4];
    #pragma unroll
    for (int g = 0; g < 4; ++g) {
      int t = t0 + tiB + g;
      #pragma unroll
      for (int j = 0; j < 4; ++j)
        qf[g][j] = *(const float4*)(q + (size_t)t * D + lane*4 + j*256);
    }
    const int wlo = max(0, t0 + tiB - WINDOW);
    const int whi = min(S, t0 + tiB + 3 + WINDOW);
    for (int s = wlo; s < whi; ++s) {
      float4 kf[4];
      #pragma unroll
      for (int j = 0; j < 4; ++j)
        kf[j] = *(const float4*)(kmat + (size_t)s * D + lane*4 + j*256);
      float acc[4];
      #pragma unroll
      for (int g = 0; g < 4; ++g) {
        float v = 0.f;
        #pragma unroll
        for (int j = 0; j < 4; ++j) {
          v = fmaf(qf[g][j].x, kf[j].x, v);
          v = fmaf(qf[g][j].y, kf[j].y, v);
          v = fmaf(qf[g][j].z, kf[j].z, v);
          v = fmaf(qf[g][j].w, kf[j].w, v);
        }
        acc[g] = v;
      }
      #pragma unroll
      for (int g = 0; g < 4; ++g) {
        float tot = wave_sum(acc[g]);
        int t = t0 + tiB + g;
        if (lane == 0 && s >= t - WINDOW && s < t + WINDOW)
          sc[tiB + g][s - lo_u] = tot;
      }
    }
  }
  __syncthreads();

  #pragma unroll
  for (int g = 0; g < 4; ++g) {
    int ti = wv * 4 + g;
    int t = t0 + ti;
    int lo = max(0, t - WINDOW), hi = min(S, t + WINDOW);
    int cnt = hi - lo, off = lo - lo_u;
    float m = 0.f;
    for (int i = lane; i < cnt; i += 64) m = fmaxf(m, sc[ti][off + i]);
    m = wave_max(m);
    float e0 = __expf(-m);
    float ssum = 0.f;
    for (int i = lane; i < cnt; i += 64) {
      float e = __expf(sc[ti][off + i] - m);
      ssum += e;
      sc[ti][off + i] = e - e0;
    }
    ssum = wave_sum(ssum);
    if (lane == 0) {
      float denom = ssum + (float)(S - cnt) * e0;
      dinv[ti] = 1.f / denom;
      e0s[ti]  = e0;
    }
  }
  __syncthreads();

  {
    const int c4 = tid * 4;
    float4 acc[TQ];
    #pragma unroll
    for (int ti = 0; ti < TQ; ++ti) acc[ti] = make_float4(0.f, 0.f, 0.f, 0.f);

    for (int su = 0; su < ucnt; su += 4) {
      float4 xr[4];
      #pragma unroll
      for (int u = 0; u < 4; ++u)
        xr[u] = *(const float4*)(x + (size_t)(lo_u + su + u) * D + c4);
      #pragma unroll
      for (int ti = 0; ti < TQ; ++ti) {
        float4 w4 = *(const float4*)&sc[ti][su];
        float wvv[4] = {w4.x, w4.y, w4.z, w4.w};
        #pragma unroll
        for (int u = 0; u < 4; ++u) {
          acc[ti].x = fmaf(wvv[u], xr[u].x, acc[ti].x);
          acc[ti].y = fmaf(wvv[u], xr[u].y, acc[ti].y);
          acc[ti].z = fmaf(wvv[u], xr[u].z, acc[ti].z);
          acc[ti].w = fmaf(wvv[u], xr[u].w, acc[ti].w);
        }
      }
    }

    float4 xsv = *(const float4*)(xsum + c4);
    #pragma unroll
    for (int ti = 0; ti < TQ; ++ti) {
      float e0 = e0s[ti], di = dinv[ti];
      float4 o;
      o.x = (acc[ti].x + e0 * xsv.x) * di;
      o.y = (acc[ti].y + e0 * xsv.y) * di;
      o.z = (acc[ti].z + e0 * xsv.z) * di;
      o.w = (acc[ti].w + e0 * xsv.w) * di;
      *(float4*)(out + (size_t)(t0 + ti) * D + c4) = o;
    }
  }
}

extern "C" void kernel_launch(void* const* d_in, const int* in_sizes, int n_in,
                              void* d_out, int out_size, void* d_ws, size_t ws_size,
                              hipStream_t stream) {
  const float* x  = (const float*)d_in[0];
  const float* Wq = (const float*)d_in[1];
  const float* bq = (const float*)d_in[2];
  const float* Wk = (const float*)d_in[3];
  const float* bk = (const float*)d_in[4];
  float* outp = (float*)d_out;

  const size_t SD = (size_t)S * D;   // 8388608
  const size_t DD = (size_t)D * D;   // 1048576

  float* q    = (float*)d_ws;
  float* kbuf = q + SD;
  float* xsum = kbuf + SD;
  unsigned short* xhi = (unsigned short*)(xsum + D);
  unsigned short* xlo = xhi + SD;
  unsigned short* wqh = xlo + SD;
  unsigned short* wql = wqh + DD;
  unsigned short* wkh = wql + DD;
  unsigned short* wkl = wkh + DD;
  size_t needed = (size_t)((char*)(wkl + DD) - (char*)d_ws);

  hipMemsetAsync(xsum, 0, D * sizeof(float), stream);

  if (ws_size >= needed) {
    split_kernel<<<SD / 1024, 256, 0, stream>>>(x,  xhi, xlo);
    split_kernel<<<DD / 1024, 256, 0, stream>>>(Wq, wqh, wql);
    split_kernel<<<DD / 1024, 256, 0, stream>>>(Wk, wkh, wkl);
    gemm_qk<<<dim3(S / 128, D / 128, 2), 256, 0, stream>>>(
        xhi, xlo, wqh, wql, wkh, wkl, bq, bk, q, kbuf);
  } else {
    proj_kernel<<<dim3(S / 64, D / 64), 256, 0, stream>>>(x, Wq, bq, Wk, bk, q, kbuf);
  }

  colsum_kernel<<<dim3(D / 256, S / 256), 256, 0, stream>>>(x, xsum);
  attn_kernel<<<dim3(S / TQ), 256, 0, stream>>>(x, q, kbuf, xsum, outp);
}

// Round 4
// 306.359 us; speedup vs baseline: 2.9014x; 1.9708x over previous
//
#include <hip/hip_runtime.h>

#define S 8192
#define D 1024
#define WINDOW 128
#define TQ 16
#define UMAX 288
#define BK 32
#define PAD 68
#define SCP 276    // sc fp32 col stride
#define PP  296    // Pt / Xt bf16 col stride (592B rows: 2-way bank alias = free)
#define NT  17     // s-tiles (272 staged k-rows)

typedef __attribute__((ext_vector_type(8))) short short8;
typedef __attribute__((ext_vector_type(4))) float floatx4;
typedef __attribute__((ext_vector_type(4))) unsigned short ushort4v;
typedef unsigned short u16t;

__device__ __forceinline__ float wave_sum(float v) {
  #pragma unroll
  for (int off = 32; off > 0; off >>= 1) v += __shfl_xor(v, off, 64);
  return v;
}
__device__ __forceinline__ float wave_max(float v) {
  #pragma unroll
  for (int off = 32; off > 0; off >>= 1) v = fmaxf(v, __shfl_xor(v, off, 64));
  return v;
}
__device__ __forceinline__ unsigned int f2bf_rn(float f) {
  unsigned int u = __float_as_uint(f);
  return (u + 0x7fffu + ((u >> 16) & 1u)) >> 16;
}

// ---------------------------------------------------------------------------
// fp32 -> (bf16 hi, bf16 lo) split
// ---------------------------------------------------------------------------
__global__ __launch_bounds__(256) void split_kernel(
    const float* __restrict__ src, u16t* __restrict__ hi, u16t* __restrict__ lo)
{
  int i = (blockIdx.x * 256 + threadIdx.x) * 4;
  float4 v = *(const float4*)(src + i);
  float f[4] = {v.x, v.y, v.z, v.w};
  ushort4v h, l;
  #pragma unroll
  for (int c = 0; c < 4; ++c) {
    unsigned int hb = f2bf_rn(f[c]);
    float hf = __uint_as_float(hb << 16);
    unsigned int lb = f2bf_rn(f[c] - hf);
    h[c] = (u16t)hb;
    l[c] = (u16t)lb;
  }
  *(ushort4v*)(hi + i) = h;
  *(ushort4v*)(lo + i) = l;
}

// ---------------------------------------------------------------------------
// x fp32 [S][D] -> xT bf16 [D][S]
// ---------------------------------------------------------------------------
__global__ __launch_bounds__(256) void transpose_x(const float* __restrict__ x,
                                                   u16t* __restrict__ xT)
{
  __shared__ float tile[64][65];
  const int s0 = blockIdx.x * 64;
  const int d0 = blockIdx.y * 64;
  const int t = threadIdx.x;
  #pragma unroll
  for (int p = 0; p < 4; ++p) {
    int r = (t >> 4) + p * 16;
    int c = (t & 15) * 4;
    float4 v = *(const float4*)(x + (size_t)(s0 + r) * D + d0 + c);
    tile[r][c+0] = v.x; tile[r][c+1] = v.y; tile[r][c+2] = v.z; tile[r][c+3] = v.w;
  }
  __syncthreads();
  #pragma unroll
  for (int p = 0; p < 4; ++p) {
    int dd = (t >> 4) + p * 16;
    int ss = (t & 15) * 4;
    ushort4v o;
    #pragma unroll
    for (int u = 0; u < 4; ++u) o[u] = (u16t)f2bf_rn(tile[ss + u][dd]);
    *(ushort4v*)(xT + (size_t)(d0 + dd) * S + s0 + ss) = o;
  }
}

// ---------------------------------------------------------------------------
// MFMA projection -> bf16 hi/lo outputs (qh,ql or kh,kl per blockIdx.z)
// ---------------------------------------------------------------------------
__global__ __launch_bounds__(256) void gemm_qk(
    const u16t* __restrict__ xhi, const u16t* __restrict__ xlo,
    const u16t* __restrict__ wqhi, const u16t* __restrict__ wqlo,
    const u16t* __restrict__ wkhi, const u16t* __restrict__ wklo,
    const float* __restrict__ bqv, const float* __restrict__ bkv,
    u16t* __restrict__ qh, u16t* __restrict__ ql,
    u16t* __restrict__ kh, u16t* __restrict__ kl)
{
  __shared__ __align__(16) u16t Ah[128 * BK];
  __shared__ __align__(16) u16t Al[128 * BK];
  __shared__ __align__(16) u16t Bh[128 * BK];
  __shared__ __align__(16) u16t Bl[128 * BK];

  const int tid  = threadIdx.x;
  const int lane = tid & 63;
  const int wv   = tid >> 6;
  const int t0   = blockIdx.x * 128;
  const int n0   = blockIdx.y * 128;

  const u16t* whi = blockIdx.z ? wkhi : wqhi;
  const u16t* wlo = blockIdx.z ? wklo : wqlo;
  const float* bias = blockIdx.z ? bkv : bqv;
  u16t* oh = blockIdx.z ? kh : qh;
  u16t* ol = blockIdx.z ? kl : ql;

  floatx4 acc[4][4] = {};

  const int m0w  = (wv & 1) * 64;
  const int n0w  = (wv >> 1) * 64;
  const int srow = lane >> 2;
  const int scol = (lane & 3) * 8;

  for (int k0 = 0; k0 < D; k0 += BK) {
    __syncthreads();
    #pragma unroll
    for (int sg = 0; sg < 2; ++sg) {
      int seg  = wv * 2 + sg;
      int arow = t0 + seg * 16 + srow;
      int brow = n0 + seg * 16 + srow;
      size_t ga = (size_t)arow * D + k0 + scol;
      size_t gb = (size_t)brow * D + k0 + scol;
      __builtin_amdgcn_global_load_lds(
          (const __attribute__((address_space(1))) void*)(xhi + ga),
          (__attribute__((address_space(3))) void*)(&Ah[seg * 512]), 16, 0, 0);
      __builtin_amdgcn_global_load_lds(
          (const __attribute__((address_space(1))) void*)(xlo + ga),
          (__attribute__((address_space(3))) void*)(&Al[seg * 512]), 16, 0, 0);
      __builtin_amdgcn_global_load_lds(
          (const __attribute__((address_space(1))) void*)(whi + gb),
          (__attribute__((address_space(3))) void*)(&Bh[seg * 512]), 16, 0, 0);
      __builtin_amdgcn_global_load_lds(
          (const __attribute__((address_space(1))) void*)(wlo + gb),
          (__attribute__((address_space(3))) void*)(&Bl[seg * 512]), 16, 0, 0);
    }
    __syncthreads();

    short8 ah[4], al[4], bh[4], bl[4];
    #pragma unroll
    for (int t = 0; t < 4; ++t) {
      int ar = (m0w + t * 16 + (lane & 15)) * BK + (lane >> 4) * 8;
      int br = (n0w + t * 16 + (lane & 15)) * BK + (lane >> 4) * 8;
      ah[t] = *(const short8*)&Ah[ar];
      al[t] = *(const short8*)&Al[ar];
      bh[t] = *(const short8*)&Bh[br];
      bl[t] = *(const short8*)&Bl[br];
    }
    #pragma unroll
    for (int mt = 0; mt < 4; ++mt)
      #pragma unroll
      for (int nt = 0; nt < 4; ++nt) {
        acc[mt][nt] = __builtin_amdgcn_mfma_f32_16x16x32_bf16(ah[mt], bh[nt], acc[mt][nt], 0, 0, 0);
        acc[mt][nt] = __builtin_amdgcn_mfma_f32_16x16x32_bf16(ah[mt], bl[nt], acc[mt][nt], 0, 0, 0);
        acc[mt][nt] = __builtin_amdgcn_mfma_f32_16x16x32_bf16(al[mt], bh[nt], acc[mt][nt], 0, 0, 0);
      }
  }

  #pragma unroll
  for (int mt = 0; mt < 4; ++mt) {
    #pragma unroll
    for (int nt = 0; nt < 4; ++nt) {
      int n = n0 + n0w + nt * 16 + (lane & 15);
      int m = t0 + m0w + mt * 16 + (lane >> 4) * 4;
      float b = bias[n];
      #pragma unroll
      for (int r = 0; r < 4; ++r) {
        float v = acc[mt][nt][r] + b;
        unsigned int hb = f2bf_rn(v);
        float hf = __uint_as_float(hb << 16);
        unsigned int lb = f2bf_rn(v - hf);
        size_t idx = (size_t)(m + r) * D + n;
        oh[idx] = (u16t)hb;
        ol[idx] = (u16t)lb;
      }
    }
  }
}

// ---------------------------------------------------------------------------
// xsum[d] = sum_t x[t][d]
// ---------------------------------------------------------------------------
__global__ __launch_bounds__(256) void colsum_kernel(const float* __restrict__ x,
                                                     float* __restrict__ xsum)
{
  int d = blockIdx.x * 256 + threadIdx.x;
  int tbase = blockIdx.y * 256;
  float s = 0.f;
  for (int t = 0; t < 256; ++t) s += x[(size_t)(tbase + t) * D + d];
  atomicAdd(&xsum[d], s);
}

// ---------------------------------------------------------------------------
// MFMA windowed attention. 512 threads (8 waves), TQ=16 q-rows per block.
//  A: scores[16][272] = qh*kh + ql*kh + qh*kl  (MFMA, d-chunks of 32)
//  B: softmax w/ zero-entry correction; P=(e-e0)/denom as bf16 in LDS
//  C: out = P @ X + (e0/denom)*xsum  (MFMA, Xt tiles staged from global xT)
// ---------------------------------------------------------------------------
__global__ __launch_bounds__(512) void attn_mfma(
    const u16t* __restrict__ qh_g, const u16t* __restrict__ ql_g,
    const u16t* __restrict__ kh_g, const u16t* __restrict__ kl_g,
    const u16t* __restrict__ xT, const float* __restrict__ xsum,
    float* __restrict__ out)
{
  __shared__ __align__(16) unsigned char lds[65088];
  u16t* kbuf = (u16t*)lds;                    // [22528 B] 272+ rows x 40 u16 (32 data + 8 pad)
  u16t* qbh  = (u16t*)(lds + 22528);          // [2048 B] 16 rows x 40 u16
  u16t* qbl  = (u16t*)(lds + 24576);          // [2048 B]
  u16t* XtL  = (u16t*)(lds);                  // [37888 B] phase C: 64 rows x 296 u16
  float* sc  = (float*)(lds + 37888);         // [16][276] fp32
  u16t* Pt   = (u16t*)(lds + 55552);          // [16][296] bf16
  float* e0d = (float*)(lds + 65024);         // [16]

  const int tid  = threadIdx.x;
  const int lane = tid & 63;
  const int w    = tid >> 6;
  int bxs = (int)blockIdx.x;
  bxs = (bxs & 7) * 64 + (bxs >> 3);          // XCD-contiguous q ranges
  const int t0   = bxs * TQ;
  const int lo_u = max(0, t0 - WINDOW);
  const int hi_u = min(S, t0 + TQ - 1 + WINDOW);
  const int ucnt = hi_u - lo_u;

  for (int i = tid; i < 16 * SCP; i += 512) sc[i] = 0.f;
  for (int i = tid; i < 16 * PP; i += 512) Pt[i] = 0;

  floatx4 accS[3] = {};

  // ---- phase A1: acc += qh*kh + ql*kh  (stage kh)
  for (int d0 = 0; d0 < D; d0 += 32) {
    __syncthreads();
    for (int j = w; j < 22; j += 8) {
      int lg = j * 64 + lane;
      int row = lg / 5;
      int part = lg - row * 5; if (part > 3) part = 3;
      int rg = lo_u + row; if (rg > S - 1) rg = S - 1;
      const u16t* g = kh_g + ((size_t)rg << 10) + d0 + part * 8;
      __builtin_amdgcn_global_load_lds(
          (const __attribute__((address_space(1))) void*)g,
          (__attribute__((address_space(3))) void*)((unsigned char*)kbuf + j * 1024), 16, 0, 0);
    }
    if (w >= 6) {
      const u16t* src = (w == 6) ? qh_g : ql_g;
      u16t* dst = (w == 6) ? qbh : qbl;
      for (int j = 0; j < 2; ++j) {
        int lg = j * 64 + lane;
        int r0 = lg / 5;
        int part = lg - r0 * 5; if (part > 3) part = 3;
        int row = r0 > 15 ? 15 : r0;
        const u16t* g = src + ((size_t)(t0 + row) << 10) + d0 + part * 8;
        __builtin_amdgcn_global_load_lds(
            (const __attribute__((address_space(1))) void*)g,
            (__attribute__((address_space(3))) void*)((unsigned char*)dst + j * 1024), 16, 0, 0);
      }
    }
    __syncthreads();
    short8 aqh = *(const short8*)((unsigned char*)qbh + (lane & 15) * 80 + (lane >> 4) * 16);
    short8 aql = *(const short8*)((unsigned char*)qbl + (lane & 15) * 80 + (lane >> 4) * 16);
    #pragma unroll
    for (int i = 0; i < 3; ++i) {
      int tl = w + 8 * i;
      if (tl >= NT) continue;
      short8 kb = *(const short8*)((unsigned char*)kbuf + (tl * 16 + (lane & 15)) * 80 + (lane >> 4) * 16);
      accS[i] = __builtin_amdgcn_mfma_f32_16x16x32_bf16(aqh, kb, accS[i], 0, 0, 0);
      accS[i] = __builtin_amdgcn_mfma_f32_16x16x32_bf16(aql, kb, accS[i], 0, 0, 0);
    }
  }

  // ---- phase A2: acc += qh*kl  (stage kl)
  for (int d0 = 0; d0 < D; d0 += 32) {
    __syncthreads();
    for (int j = w; j < 22; j += 8) {
      int lg = j * 64 + lane;
      int row = lg / 5;
      int part = lg - row * 5; if (part > 3) part = 3;
      int rg = lo_u + row; if (rg > S - 1) rg = S - 1;
      const u16t* g = kl_g + ((size_t)rg << 10) + d0 + part * 8;
      __builtin_amdgcn_global_load_lds(
          (const __attribute__((address_space(1))) void*)g,
          (__attribute__((address_space(3))) void*)((unsigned char*)kbuf + j * 1024), 16, 0, 0);
    }
    if (w == 6) {
      for (int j = 0; j < 2; ++j) {
        int lg = j * 64 + lane;
        int r0 = lg / 5;
        int part = lg - r0 * 5; if (part > 3) part = 3;
        int row = r0 > 15 ? 15 : r0;
        const u16t* g = qh_g + ((size_t)(t0 + row) << 10) + d0 + part * 8;
        __builtin_amdgcn_global_load_lds(
            (const __attribute__((address_space(1))) void*)g,
            (__attribute__((address_space(3))) void*)((unsigned char*)qbh + j * 1024), 16, 0, 0);
      }
    }
    __syncthreads();
    short8 aqh = *(const short8*)((unsigned char*)qbh + (lane & 15) * 80 + (lane >> 4) * 16);
    #pragma unroll
    for (int i = 0; i < 3; ++i) {
      int tl = w + 8 * i;
      if (tl >= NT) continue;
      short8 kb = *(const short8*)((unsigned char*)kbuf + (tl * 16 + (lane & 15)) * 80 + (lane >> 4) * 16);
      accS[i] = __builtin_amdgcn_mfma_f32_16x16x32_bf16(aqh, kb, accS[i], 0, 0, 0);
    }
  }
  __syncthreads();

  // ---- write scores (window-masked); C layout: m=(lane>>4)*4+r, n=lane&15
  {
    const int n_loc = lane & 15;
    #pragma unroll
    for (int i = 0; i < 3; ++i) {
      int tl = w + 8 * i;
      if (tl >= NT) continue;
      int s_loc = tl * 16 + n_loc;
      int s_g = lo_u + s_loc;
      #pragma unroll
      for (int r = 0; r < 4; ++r) {
        int m = (lane >> 4) * 4 + r;
        int t = t0 + m;
        if (s_g >= t - WINDOW && s_g < t + WINDOW && s_g < S)
          sc[m * SCP + s_loc] = accS[i][r];
      }
    }
  }
  __syncthreads();

  // ---- softmax with zero-entry correction; fold 1/denom into bf16 P
  #pragma unroll
  for (int g = 0; g < 2; ++g) {
    int m = w * 2 + g;
    int t = t0 + m;
    int lo = max(0, t - WINDOW), hi = min(S, t + WINDOW);
    int cnt = hi - lo, off = lo - lo_u;
    float mx = 0.f;
    for (int i = lane; i < cnt; i += 64) mx = fmaxf(mx, sc[m * SCP + off + i]);
    mx = wave_max(mx);
    float e0 = __expf(-mx);
    float ss = 0.f;
    for (int i = lane; i < cnt; i += 64) ss += __expf(sc[m * SCP + off + i] - mx);
    ss = wave_sum(ss);
    float dinv = 1.f / (ss + (float)(S - cnt) * e0);
    for (int i = lane; i < cnt; i += 64) {
      float e = __expf(sc[m * SCP + off + i] - mx);
      Pt[m * PP + off + i] = (u16t)f2bf_rn((e - e0) * dinv);
    }
    if (lane == 0) e0d[m] = e0 * dinv;
  }

  // ---- phase C: out = P @ X + e0d*xsum, d-chunks of 64 (Xt from global xT)
  for (int d0 = 0; d0 < D; d0 += 64) {
    __syncthreads();
    for (int j = w; j < 37; j += 8) {
      int lg = j * 64 + lane;
      int row = lg / 37;
      int chunk = lg - row * 37;
      int cg = lo_u + chunk * 8; if (cg > S - 8) cg = S - 8;
      const u16t* g = xT + (((size_t)(d0 + row)) << 13) + cg;
      __builtin_amdgcn_global_load_lds(
          (const __attribute__((address_space(1))) void*)g,
          (__attribute__((address_space(3))) void*)((unsigned char*)XtL + j * 1024), 16, 0, 0);
    }
    __syncthreads();
    if (w < 4) {
      floatx4 accO = {0.f, 0.f, 0.f, 0.f};
      #pragma unroll
      for (int c = 0; c < 9; ++c) {
        short8 pf = *(const short8*)((unsigned char*)Pt + (lane & 15) * (PP * 2) + c * 64 + (lane >> 4) * 16);
        short8 xf = *(const short8*)((unsigned char*)XtL + (w * 16 + (lane & 15)) * (PP * 2) + c * 64 + (lane >> 4) * 16);
        accO = __builtin_amdgcn_mfma_f32_16x16x32_bf16(pf, xf, accO, 0, 0, 0);
      }
      int n_g = d0 + w * 16 + (lane & 15);
      float xs = xsum[n_g];
      #pragma unroll
      for (int r = 0; r < 4; ++r) {
        int m = (lane >> 4) * 4 + r;
        out[(size_t)(t0 + m) * D + n_g] = accO[r] + e0d[m] * xs;
      }
    }
  }
}

// ---------------------------------------------------------------------------
// Fallback path (round-3 verified): fp32 proj + VALU attn
// ---------------------------------------------------------------------------
__global__ __launch_bounds__(256) void proj_kernel(
    const float* __restrict__ x, const float* __restrict__ Wq,
    const float* __restrict__ bqv, const float* __restrict__ Wk,
    const float* __restrict__ bkv, float* __restrict__ qout,
    float* __restrict__ kout)
{
  __shared__ __align__(16) float xs[BK][PAD];
  __shared__ __align__(16) float wqs[BK][PAD];
  __shared__ __align__(16) float wks[BK][PAD];
  const int tid = threadIdx.x;
  const int tx = tid & 15, ty = tid >> 4;
  const int t0 = blockIdx.x * 64, i0 = blockIdx.y * 64;
  float accq[4][4] = {}, acck[4][4] = {};
  const int lrow0 = tid >> 3, lc4 = (tid & 7) * 4;
  for (int k0 = 0; k0 < D; k0 += BK) {
    __syncthreads();
    #pragma unroll
    for (int p = 0; p < 2; ++p) {
      int row = lrow0 + p * 32;
      float4 a = *(const float4*)(x  + (size_t)(t0 + row) * D + k0 + lc4);
      float4 b = *(const float4*)(Wq + (size_t)(i0 + row) * D + k0 + lc4);
      float4 c = *(const float4*)(Wk + (size_t)(i0 + row) * D + k0 + lc4);
      xs [lc4+0][row]=a.x; xs [lc4+1][row]=a.y; xs [lc4+2][row]=a.z; xs [lc4+3][row]=a.w;
      wqs[lc4+0][row]=b.x; wqs[lc4+1][row]=b.y; wqs[lc4+2][row]=b.z; wqs[lc4+3][row]=b.w;
      wks[lc4+0][row]=c.x; wks[lc4+1][row]=c.y; wks[lc4+2][row]=c.z; wks[lc4+3][row]=c.w;
    }
    __syncthreads();
    #pragma unroll
    for (int kk = 0; kk < BK; ++kk) {
      float4 av = *(const float4*)&xs [kk][ty*4];
      float4 bv = *(const float4*)&wqs[kk][tx*4];
      float4 cv = *(const float4*)&wks[kk][tx*4];
      float a[4] = {av.x, av.y, av.z, av.w};
      float b[4] = {bv.x, bv.y, bv.z, bv.w};
      float c[4] = {cv.x, cv.y, cv.z, cv.w};
      #pragma unroll
      for (int r = 0; r < 4; ++r)
        #pragma unroll
        for (int cc = 0; cc < 4; ++cc) {
          accq[r][cc] = fmaf(a[r], b[cc], accq[r][cc]);
          acck[r][cc] = fmaf(a[r], c[cc], acck[r][cc]);
        }
    }
  }
  float4 bq4 = *(const float4*)(bqv + i0 + tx*4);
  float4 bk4 = *(const float4*)(bkv + i0 + tx*4);
  #pragma unroll
  for (int r = 0; r < 4; ++r) {
    int trow = t0 + ty*4 + r;
    float4 oq = { accq[r][0]+bq4.x, accq[r][1]+bq4.y, accq[r][2]+bq4.z, accq[r][3]+bq4.w };
    float4 ok = { acck[r][0]+bk4.x, acck[r][1]+bk4.y, acck[r][2]+bk4.z, acck[r][3]+bk4.w };
    *(float4*)(qout + (size_t)trow * D + i0 + tx*4) = oq;
    *(float4*)(kout + (size_t)trow * D + i0 + tx*4) = ok;
  }
}

__global__ __launch_bounds__(256) void attn_kernel(
    const float* __restrict__ x, const float* __restrict__ q,
    const float* __restrict__ kmat, const float* __restrict__ xsum,
    float* __restrict__ out)
{
  __shared__ __align__(16) float scl[TQ][UMAX];
  __shared__ float e0s[TQ], dinv[TQ];
  const int tid = threadIdx.x, lane = tid & 63, wv = tid >> 6;
  const int t0 = blockIdx.x * TQ;
  const int lo_u = max(0, t0 - WINDOW);
  const int hi_u = min(S, t0 + TQ - 1 + WINDOW);
  const int ucnt = hi_u - lo_u;
  for (int i = tid; i < TQ * UMAX; i += 256) (&scl[0][0])[i] = 0.f;
  __syncthreads();
  {
    const int tiB = wv * 4;
    float4 qf[4][4];
    #pragma unroll
    for (int g = 0; g < 4; ++g) {
      int t = t0 + tiB + g;
      #pragma unroll
      for (int j = 0; j < 4; ++j)
        qf[g][j] = *(const float4*)(q + (size_t)t * D + lane*4 + j*256);
    }
    const int wlo = max(0, t0 + tiB - WINDOW);
    const int whi = min(S, t0 + tiB + 3 + WINDOW);
    for (int s = wlo; s < whi; ++s) {
      float4 kf[4];
      #pragma unroll
      for (int j = 0; j < 4; ++j)
        kf[j] = *(const float4*)(kmat + (size_t)s * D + lane*4 + j*256);
      float acc[4];
      #pragma unroll
      for (int g = 0; g < 4; ++g) {
        float v = 0.f;
        #pragma unroll
        for (int j = 0; j < 4; ++j) {
          v = fmaf(qf[g][j].x, kf[j].x, v);
          v = fmaf(qf[g][j].y, kf[j].y, v);
          v = fmaf(qf[g][j].z, kf[j].z, v);
          v = fmaf(qf[g][j].w, kf[j].w, v);
        }
        acc[g] = v;
      }
      #pragma unroll
      for (int g = 0; g < 4; ++g) {
        float tot = wave_sum(acc[g]);
        int t = t0 + tiB + g;
        if (lane == 0 && s >= t - WINDOW && s < t + WINDOW)
          scl[tiB + g][s - lo_u] = tot;
      }
    }
  }
  __syncthreads();
  #pragma unroll
  for (int g = 0; g < 4; ++g) {
    int ti = wv * 4 + g;
    int t = t0 + ti;
    int lo = max(0, t - WINDOW), hi = min(S, t + WINDOW);
    int cnt = hi - lo, off = lo - lo_u;
    float m = 0.f;
    for (int i = lane; i < cnt; i += 64) m = fmaxf(m, scl[ti][off + i]);
    m = wave_max(m);
    float e0 = __expf(-m);
    float ssum = 0.f;
    for (int i = lane; i < cnt; i += 64) {
      float e = __expf(scl[ti][off + i] - m);
      ssum += e;
      scl[ti][off + i] = e - e0;
    }
    ssum = wave_sum(ssum);
    if (lane == 0) {
      dinv[ti] = 1.f / (ssum + (float)(S - cnt) * e0);
      e0s[ti] = e0;
    }
  }
  __syncthreads();
  {
    const int c4 = tid * 4;
    float4 acc[TQ];
    #pragma unroll
    for (int ti = 0; ti < TQ; ++ti) acc[ti] = make_float4(0.f, 0.f, 0.f, 0.f);
    for (int su = 0; su < ucnt; su += 4) {
      float4 xr[4];
      #pragma unroll
      for (int u = 0; u < 4; ++u)
        xr[u] = *(const float4*)(x + (size_t)(lo_u + su + u) * D + c4);
      #pragma unroll
      for (int ti = 0; ti < TQ; ++ti) {
        float4 w4 = *(const float4*)&scl[ti][su];
        float wvv[4] = {w4.x, w4.y, w4.z, w4.w};
        #pragma unroll
        for (int u = 0; u < 4; ++u) {
          acc[ti].x = fmaf(wvv[u], xr[u].x, acc[ti].x);
          acc[ti].y = fmaf(wvv[u], xr[u].y, acc[ti].y);
          acc[ti].z = fmaf(wvv[u], xr[u].z, acc[ti].z);
          acc[ti].w = fmaf(wvv[u], xr[u].w, acc[ti].w);
        }
      }
    }
    float4 xsv = *(const float4*)(xsum + c4);
    #pragma unroll
    for (int ti = 0; ti < TQ; ++ti) {
      float e0 = e0s[ti], di = dinv[ti];
      float4 o;
      o.x = (acc[ti].x + e0 * xsv.x) * di;
      o.y = (acc[ti].y + e0 * xsv.y) * di;
      o.z = (acc[ti].z + e0 * xsv.z) * di;
      o.w = (acc[ti].w + e0 * xsv.w) * di;
      *(float4*)(out + (size_t)(t0 + ti) * D + c4) = o;
    }
  }
}

extern "C" void kernel_launch(void* const* d_in, const int* in_sizes, int n_in,
                              void* d_out, int out_size, void* d_ws, size_t ws_size,
                              hipStream_t stream) {
  const float* x  = (const float*)d_in[0];
  const float* Wq = (const float*)d_in[1];
  const float* bq = (const float*)d_in[2];
  const float* Wk = (const float*)d_in[3];
  const float* bk = (const float*)d_in[4];
  float* outp = (float*)d_out;

  const size_t SD = (size_t)S * D;
  const size_t DD = (size_t)D * D;

  // MFMA-path workspace layout
  float* xsum = (float*)d_ws;                       // 4 KB
  u16t* xhi = (u16t*)(xsum + D);
  u16t* xlo = xhi + SD;
  u16t* wqh = xlo + SD;
  u16t* wql = wqh + DD;
  u16t* wkh = wql + DD;
  u16t* wkl = wkh + DD;
  u16t* qh  = wkl + DD;
  u16t* ql  = qh + SD;
  u16t* kh  = ql + SD;
  u16t* kl  = kh + SD;
  u16t* xT  = kl + SD;
  size_t needed = (size_t)((char*)(xT + SD) - (char*)d_ws);

  hipMemsetAsync(xsum, 0, D * sizeof(float), stream);
  colsum_kernel<<<dim3(D / 256, S / 256), 256, 0, stream>>>(x, xsum);

  if (ws_size >= needed) {
    split_kernel<<<SD / 1024, 256, 0, stream>>>(x,  xhi, xlo);
    split_kernel<<<DD / 1024, 256, 0, stream>>>(Wq, wqh, wql);
    split_kernel<<<DD / 1024, 256, 0, stream>>>(Wk, wkh, wkl);
    transpose_x<<<dim3(S / 64, D / 64), 256, 0, stream>>>(x, xT);
    gemm_qk<<<dim3(S / 128, D / 128, 2), 256, 0, stream>>>(
        xhi, xlo, wqh, wql, wkh, wkl, bq, bk, qh, ql, kh, kl);
    attn_mfma<<<S / TQ, 512, 0, stream>>>(qh, ql, kh, kl, xT, xsum, outp);
  } else {
    // fallback: fp32 projections + VALU attention
    float* q    = (float*)(xsum + D);
    float* kbuf = q + SD;
    proj_kernel<<<dim3(S / 64, D / 64), 256, 0, stream>>>(x, Wq, bq, Wk, bk, q, kbuf);
    attn_kernel<<<S / TQ, 256, 0, stream>>>(x, q, kbuf, xsum, outp);
  }
}

// Round 5
// 296.951 us; speedup vs baseline: 2.9934x; 1.0317x over previous
//
#include <hip/hip_runtime.h>

#define S 8192
#define D 1024
#define WINDOW 128
#define TQ 16
#define UMAX 288
#define BK 32
#define PAD 68
#define BAND 384   // band width: s in [t_tile-128, t_tile+256)

typedef __attribute__((ext_vector_type(8))) short short8;
typedef __attribute__((ext_vector_type(4))) float floatx4;
typedef __attribute__((ext_vector_type(4))) unsigned short ushort4v;
typedef unsigned short u16t;

__device__ __forceinline__ float wave_sum(float v) {
  #pragma unroll
  for (int off = 32; off > 0; off >>= 1) v += __shfl_xor(v, off, 64);
  return v;
}
__device__ __forceinline__ float wave_max(float v) {
  #pragma unroll
  for (int off = 32; off > 0; off >>= 1) v = fmaxf(v, __shfl_xor(v, off, 64));
  return v;
}
__device__ __forceinline__ unsigned int f2bf_rn(float f) {
  unsigned int u = __float_as_uint(f);
  return (u + 0x7fffu + ((u >> 16) & 1u)) >> 16;
}

// ---------------------------------------------------------------------------
// fp32 -> (bf16 hi, bf16 lo) split
// ---------------------------------------------------------------------------
__global__ __launch_bounds__(256) void split_kernel(
    const float* __restrict__ src, u16t* __restrict__ hi, u16t* __restrict__ lo)
{
  int i = (blockIdx.x * 256 + threadIdx.x) * 4;
  float4 v = *(const float4*)(src + i);
  float f[4] = {v.x, v.y, v.z, v.w};
  ushort4v h, l;
  #pragma unroll
  for (int c = 0; c < 4; ++c) {
    unsigned int hb = f2bf_rn(f[c]);
    float hf = __uint_as_float(hb << 16);
    unsigned int lb = f2bf_rn(f[c] - hf);
    h[c] = (u16t)hb;
    l[c] = (u16t)lb;
  }
  *(ushort4v*)(hi + i) = h;
  *(ushort4v*)(lo + i) = l;
}

// ---------------------------------------------------------------------------
// x fp32 [S][D] -> xT bf16 [D][S]
// ---------------------------------------------------------------------------
__global__ __launch_bounds__(256) void transpose_x(const float* __restrict__ x,
                                                   u16t* __restrict__ xT)
{
  __shared__ float tile[64][65];
  const int s0 = blockIdx.x * 64;
  const int d0 = blockIdx.y * 64;
  const int t = threadIdx.x;
  #pragma unroll
  for (int p = 0; p < 4; ++p) {
    int r = (t >> 4) + p * 16;
    int c = (t & 15) * 4;
    float4 v = *(const float4*)(x + (size_t)(s0 + r) * D + d0 + c);
    tile[r][c+0] = v.x; tile[r][c+1] = v.y; tile[r][c+2] = v.z; tile[r][c+3] = v.w;
  }
  __syncthreads();
  #pragma unroll
  for (int p = 0; p < 4; ++p) {
    int dd = (t >> 4) + p * 16;
    int ss = (t & 15) * 4;
    ushort4v o;
    #pragma unroll
    for (int u = 0; u < 4; ++u) o[u] = (u16t)f2bf_rn(tile[ss + u][dd]);
    *(ushort4v*)(xT + (size_t)(d0 + dd) * S + s0 + ss) = o;
  }
}

// ---------------------------------------------------------------------------
// MFMA projection -> bf16 hi/lo outputs (qh,ql or kh,kl per blockIdx.z)
// LDS chunk-XOR swizzle: stage global chunk c'^((row>>1)&3) into slot c',
// read slot c^((row>>1)&3) -> 2-way bank aliasing only (free).
// ---------------------------------------------------------------------------
__global__ __launch_bounds__(256) void gemm_qk(
    const u16t* __restrict__ xhi, const u16t* __restrict__ xlo,
    const u16t* __restrict__ wqhi, const u16t* __restrict__ wqlo,
    const u16t* __restrict__ wkhi, const u16t* __restrict__ wklo,
    const float* __restrict__ bqv, const float* __restrict__ bkv,
    u16t* __restrict__ qh, u16t* __restrict__ ql,
    u16t* __restrict__ kh, u16t* __restrict__ kl)
{
  __shared__ __align__(16) u16t Ah[128 * BK];
  __shared__ __align__(16) u16t Al[128 * BK];
  __shared__ __align__(16) u16t Bh[128 * BK];
  __shared__ __align__(16) u16t Bl[128 * BK];

  const int tid  = threadIdx.x;
  const int lane = tid & 63;
  const int wv   = tid >> 6;
  const int t0   = blockIdx.x * 128;
  const int n0   = blockIdx.y * 128;

  const u16t* whi = blockIdx.z ? wkhi : wqhi;
  const u16t* wlo = blockIdx.z ? wklo : wqlo;
  const float* bias = blockIdx.z ? bkv : bqv;
  u16t* oh = blockIdx.z ? kh : qh;
  u16t* ol = blockIdx.z ? kl : ql;

  floatx4 acc[4][4] = {};

  const int m0w  = (wv & 1) * 64;
  const int n0w  = (wv >> 1) * 64;
  const int srow = lane >> 2;
  const int scol = (((lane & 3) ^ ((lane >> 3) & 3))) * 8;   // swizzled global chunk
  const int p8   = (((lane >> 4) ^ ((lane >> 1) & 3))) * 8;  // swizzled LDS slot

  for (int k0 = 0; k0 < D; k0 += BK) {
    __syncthreads();
    #pragma unroll
    for (int sg = 0; sg < 2; ++sg) {
      int seg  = wv * 2 + sg;
      int arow = t0 + seg * 16 + srow;
      int brow = n0 + seg * 16 + srow;
      size_t ga = (size_t)arow * D + k0 + scol;
      size_t gb = (size_t)brow * D + k0 + scol;
      __builtin_amdgcn_global_load_lds(
          (const __attribute__((address_space(1))) void*)(xhi + ga),
          (__attribute__((address_space(3))) void*)(&Ah[seg * 512]), 16, 0, 0);
      __builtin_amdgcn_global_load_lds(
          (const __attribute__((address_space(1))) void*)(xlo + ga),
          (__attribute__((address_space(3))) void*)(&Al[seg * 512]), 16, 0, 0);
      __builtin_amdgcn_global_load_lds(
          (const __attribute__((address_space(1))) void*)(whi + gb),
          (__attribute__((address_space(3))) void*)(&Bh[seg * 512]), 16, 0, 0);
      __builtin_amdgcn_global_load_lds(
          (const __attribute__((address_space(1))) void*)(wlo + gb),
          (__attribute__((address_space(3))) void*)(&Bl[seg * 512]), 16, 0, 0);
    }
    __syncthreads();

    short8 ah[4], al[4], bh[4], bl[4];
    #pragma unroll
    for (int t = 0; t < 4; ++t) {
      int ar = (m0w + t * 16 + (lane & 15)) * BK + p8;
      int br = (n0w + t * 16 + (lane & 15)) * BK + p8;
      ah[t] = *(const short8*)&Ah[ar];
      al[t] = *(const short8*)&Al[ar];
      bh[t] = *(const short8*)&Bh[br];
      bl[t] = *(const short8*)&Bl[br];
    }
    #pragma unroll
    for (int mt = 0; mt < 4; ++mt)
      #pragma unroll
      for (int nt = 0; nt < 4; ++nt) {
        acc[mt][nt] = __builtin_amdgcn_mfma_f32_16x16x32_bf16(ah[mt], bh[nt], acc[mt][nt], 0, 0, 0);
        acc[mt][nt] = __builtin_amdgcn_mfma_f32_16x16x32_bf16(ah[mt], bl[nt], acc[mt][nt], 0, 0, 0);
        acc[mt][nt] = __builtin_amdgcn_mfma_f32_16x16x32_bf16(al[mt], bh[nt], acc[mt][nt], 0, 0, 0);
      }
  }

  #pragma unroll
  for (int mt = 0; mt < 4; ++mt) {
    #pragma unroll
    for (int nt = 0; nt < 4; ++nt) {
      int n = n0 + n0w + nt * 16 + (lane & 15);
      int m = t0 + m0w + mt * 16 + (lane >> 4) * 4;
      float b = bias[n];
      #pragma unroll
      for (int r = 0; r < 4; ++r) {
        float v = acc[mt][nt][r] + b;
        unsigned int hb = f2bf_rn(v);
        float hf = __uint_as_float(hb << 16);
        unsigned int lb = f2bf_rn(v - hf);
        size_t idx = (size_t)(m + r) * D + n;
        oh[idx] = (u16t)hb;
        ol[idx] = (u16t)lb;
      }
    }
  }
}

// ---------------------------------------------------------------------------
// xsum[d] = sum_t x[t][d]
// ---------------------------------------------------------------------------
__global__ __launch_bounds__(256) void colsum_kernel(const float* __restrict__ x,
                                                     float* __restrict__ xsum)
{
  int d = blockIdx.x * 256 + threadIdx.x;
  int tbase = blockIdx.y * 256;
  float s = 0.f;
  for (int t = 0; t < 256; ++t) s += x[(size_t)(tbase + t) * D + d];
  atomicAdd(&xsum[d], s);
}

// ---------------------------------------------------------------------------
// Banded QK^T: band[t][j] = q_t . k_s  (s = t_tile-128+j), masked to window.
// Grid (64 t-tiles, 3 s-subtiles). Same structure/swizzle as gemm_qk.
// ---------------------------------------------------------------------------
__global__ __launch_bounds__(256) void scores_kernel(
    const u16t* __restrict__ qh, const u16t* __restrict__ ql,
    const u16t* __restrict__ kh, const u16t* __restrict__ kl,
    float* __restrict__ band)
{
  __shared__ __align__(16) u16t Ah[128 * BK];
  __shared__ __align__(16) u16t Al[128 * BK];
  __shared__ __align__(16) u16t Bh[128 * BK];
  __shared__ __align__(16) u16t Bl[128 * BK];

  const int tid  = threadIdx.x;
  const int lane = tid & 63;
  const int wv   = tid >> 6;
  const int t0   = blockIdx.x * 128;
  const int jt   = blockIdx.y;                 // 0..2
  const int s_base = t0 - 128 + jt * 128;

  floatx4 acc[4][4] = {};

  const int m0w  = (wv & 1) * 64;
  const int n0w  = (wv >> 1) * 64;
  const int srow = lane >> 2;
  const int scol = (((lane & 3) ^ ((lane >> 3) & 3))) * 8;
  const int p8   = (((lane >> 4) ^ ((lane >> 1) & 3))) * 8;

  for (int k0 = 0; k0 < D; k0 += BK) {
    __syncthreads();
    #pragma unroll
    for (int sg = 0; sg < 2; ++sg) {
      int seg  = wv * 2 + sg;
      int arow = t0 + seg * 16 + srow;
      int brow = s_base + seg * 16 + srow;
      brow = min(max(brow, 0), S - 1);         // clamp; masked at epilogue
      size_t ga = (size_t)arow * D + k0 + scol;
      size_t gb = (size_t)brow * D + k0 + scol;
      __builtin_amdgcn_global_load_lds(
          (const __attribute__((address_space(1))) void*)(qh + ga),
          (__attribute__((address_space(3))) void*)(&Ah[seg * 512]), 16, 0, 0);
      __builtin_amdgcn_global_load_lds(
          (const __attribute__((address_space(1))) void*)(ql + ga),
          (__attribute__((address_space(3))) void*)(&Al[seg * 512]), 16, 0, 0);
      __builtin_amdgcn_global_load_lds(
          (const __attribute__((address_space(1))) void*)(kh + gb),
          (__attribute__((address_space(3))) void*)(&Bh[seg * 512]), 16, 0, 0);
      __builtin_amdgcn_global_load_lds(
          (const __attribute__((address_space(1))) void*)(kl + gb),
          (__attribute__((address_space(3))) void*)(&Bl[seg * 512]), 16, 0, 0);
    }
    __syncthreads();

    short8 ah[4], al[4], bh[4], bl[4];
    #pragma unroll
    for (int t = 0; t < 4; ++t) {
      int ar = (m0w + t * 16 + (lane & 15)) * BK + p8;
      int br = (n0w + t * 16 + (lane & 15)) * BK + p8;
      ah[t] = *(const short8*)&Ah[ar];
      al[t] = *(const short8*)&Al[ar];
      bh[t] = *(const short8*)&Bh[br];
      bl[t] = *(const short8*)&Bl[br];
    }
    #pragma unroll
    for (int mt = 0; mt < 4; ++mt)
      #pragma unroll
      for (int nt = 0; nt < 4; ++nt) {
        acc[mt][nt] = __builtin_amdgcn_mfma_f32_16x16x32_bf16(ah[mt], bh[nt], acc[mt][nt], 0, 0, 0);
        acc[mt][nt] = __builtin_amdgcn_mfma_f32_16x16x32_bf16(ah[mt], bl[nt], acc[mt][nt], 0, 0, 0);
        acc[mt][nt] = __builtin_amdgcn_mfma_f32_16x16x32_bf16(al[mt], bh[nt], acc[mt][nt], 0, 0, 0);
      }
  }

  #pragma unroll
  for (int mt = 0; mt < 4; ++mt) {
    #pragma unroll
    for (int nt = 0; nt < 4; ++nt) {
      int n_loc = n0w + nt * 16 + (lane & 15);
      int s = s_base + n_loc;
      #pragma unroll
      for (int r = 0; r < 4; ++r) {
        int m_loc = m0w + mt * 16 + (lane >> 4) * 4 + r;
        int t = t0 + m_loc;
        bool inwin = (s >= t - WINDOW) && (s < t + WINDOW) && (s >= 0) && (s < S);
        band[(size_t)t * BAND + jt * 128 + n_loc] = inwin ? acc[mt][nt][r] : 0.f;
      }
    }
  }
}

// ---------------------------------------------------------------------------
// Softmax over the band. Zero slots automatically give P=0; denom adds
// (S-384)*e0 for the out-of-band zeros. One wave per row.
// ---------------------------------------------------------------------------
__global__ __launch_bounds__(256) void softmax_kernel(
    const float* __restrict__ band, u16t* __restrict__ Pb, float* __restrict__ e0d)
{
  const int lane = threadIdx.x & 63;
  const int w    = threadIdx.x >> 6;
  const int t    = blockIdx.x * 4 + w;
  const float* row = band + (size_t)t * BAND;

  float v[6];
  float mx = 0.f;                               // zeros always present
  #pragma unroll
  for (int i = 0; i < 6; ++i) {
    v[i] = row[i * 64 + lane];
    mx = fmaxf(mx, v[i]);
  }
  mx = wave_max(mx);
  float e0 = __expf(-mx);
  float ss = 0.f;
  #pragma unroll
  for (int i = 0; i < 6; ++i) {
    v[i] = __expf(v[i] - mx);
    ss += v[i];
  }
  ss = wave_sum(ss);
  float dinv = 1.f / (ss + (float)(S - BAND) * e0);
  #pragma unroll
  for (int i = 0; i < 6; ++i)
    Pb[(size_t)t * BAND + i * 64 + lane] = (u16t)f2bf_rn((v[i] - e0) * dinv);
  if (lane == 0) e0d[t] = e0 * dinv;
}

// ---------------------------------------------------------------------------
// PV: out[t][d] = sum_j Pb[t][j] * x[origin+j][d] + e0d[t]*xsum[d].
// A = Pb rows, B = xT rows (cols s = origin+j, chunk-clamped; P=0 kills OOB).
// ---------------------------------------------------------------------------
__global__ __launch_bounds__(256) void pv_kernel(
    const u16t* __restrict__ Pb, const u16t* __restrict__ xT,
    const float* __restrict__ e0d, const float* __restrict__ xsum,
    float* __restrict__ out)
{
  __shared__ __align__(16) u16t Ab[128 * BK];
  __shared__ __align__(16) u16t Bb[128 * BK];

  const int tid  = threadIdx.x;
  const int lane = tid & 63;
  const int wv   = tid >> 6;
  const int t0   = blockIdx.x * 128;
  const int d0   = blockIdx.y * 128;
  const int origin = t0 - 128;

  floatx4 acc[4][4] = {};

  const int m0w  = (wv & 1) * 64;
  const int n0w  = (wv >> 1) * 64;
  const int srow = lane >> 2;
  const int scol = (((lane & 3) ^ ((lane >> 3) & 3))) * 8;
  const int p8   = (((lane >> 4) ^ ((lane >> 1) & 3))) * 8;

  for (int k0 = 0; k0 < BAND; k0 += BK) {
    __syncthreads();
    #pragma unroll
    for (int sg = 0; sg < 2; ++sg) {
      int seg  = wv * 2 + sg;
      int arow = t0 + seg * 16 + srow;
      int brow = d0 + seg * 16 + srow;
      int s_g  = origin + k0 + scol;             // 8-aligned chunk, fully in/out
      s_g = min(max(s_g, 0), S - 8);
      size_t ga = (size_t)arow * BAND + k0 + scol;
      size_t gb = (size_t)brow * S + s_g;
      __builtin_amdgcn_global_load_lds(
          (const __attribute__((address_space(1))) void*)(Pb + ga),
          (__attribute__((address_space(3))) void*)(&Ab[seg * 512]), 16, 0, 0);
      __builtin_amdgcn_global_load_lds(
          (const __attribute__((address_space(1))) void*)(xT + gb),
          (__attribute__((address_space(3))) void*)(&Bb[seg * 512]), 16, 0, 0);
    }
    __syncthreads();

    short8 af[4], bf[4];
    #pragma unroll
    for (int t = 0; t < 4; ++t) {
      int ar = (m0w + t * 16 + (lane & 15)) * BK + p8;
      int br = (n0w + t * 16 + (lane & 15)) * BK + p8;
      af[t] = *(const short8*)&Ab[ar];
      bf[t] = *(const short8*)&Bb[br];
    }
    #pragma unroll
    for (int mt = 0; mt < 4; ++mt)
      #pragma unroll
      for (int nt = 0; nt < 4; ++nt)
        acc[mt][nt] = __builtin_amdgcn_mfma_f32_16x16x32_bf16(af[mt], bf[nt], acc[mt][nt], 0, 0, 0);
  }

  #pragma unroll
  for (int mt = 0; mt < 4; ++mt) {
    #pragma unroll
    for (int nt = 0; nt < 4; ++nt) {
      int n_g = d0 + n0w + nt * 16 + (lane & 15);
      float xs = xsum[n_g];
      #pragma unroll
      for (int r = 0; r < 4; ++r) {
        int m_g = t0 + m0w + mt * 16 + (lane >> 4) * 4 + r;
        out[(size_t)m_g * D + n_g] = acc[mt][nt][r] + e0d[m_g] * xs;
      }
    }
  }
}

// ---------------------------------------------------------------------------
// Fallback path (round-3 verified): fp32 proj + VALU attn
// ---------------------------------------------------------------------------
__global__ __launch_bounds__(256) void proj_kernel(
    const float* __restrict__ x, const float* __restrict__ Wq,
    const float* __restrict__ bqv, const float* __restrict__ Wk,
    const float* __restrict__ bkv, float* __restrict__ qout,
    float* __restrict__ kout)
{
  __shared__ __align__(16) float xs[BK][PAD];
  __shared__ __align__(16) float wqs[BK][PAD];
  __shared__ __align__(16) float wks[BK][PAD];
  const int tid = threadIdx.x;
  const int tx = tid & 15, ty = tid >> 4;
  const int t0 = blockIdx.x * 64, i0 = blockIdx.y * 64;
  float accq[4][4] = {}, acck[4][4] = {};
  const int lrow0 = tid >> 3, lc4 = (tid & 7) * 4;
  for (int k0 = 0; k0 < D; k0 += BK) {
    __syncthreads();
    #pragma unroll
    for (int p = 0; p < 2; ++p) {
      int row = lrow0 + p * 32;
      float4 a = *(const float4*)(x  + (size_t)(t0 + row) * D + k0 + lc4);
      float4 b = *(const float4*)(Wq + (size_t)(i0 + row) * D + k0 + lc4);
      float4 c = *(const float4*)(Wk + (size_t)(i0 + row) * D + k0 + lc4);
      xs [lc4+0][row]=a.x; xs [lc4+1][row]=a.y; xs [lc4+2][row]=a.z; xs [lc4+3][row]=a.w;
      wqs[lc4+0][row]=b.x; wqs[lc4+1][row]=b.y; wqs[lc4+2][row]=b.z; wqs[lc4+3][row]=b.w;
      wks[lc4+0][row]=c.x; wks[lc4+1][row]=c.y; wks[lc4+2][row]=c.z; wks[lc4+3][row]=c.w;
    }
    __syncthreads();
    #pragma unroll
    for (int kk = 0; kk < BK; ++kk) {
      float4 av = *(const float4*)&xs [kk][ty*4];
      float4 bv = *(const float4*)&wqs[kk][tx*4];
      float4 cv = *(const float4*)&wks[kk][tx*4];
      float a[4] = {av.x, av.y, av.z, av.w};
      float b[4] = {bv.x, bv.y, bv.z, bv.w};
      float c[4] = {cv.x, cv.y, cv.z, cv.w};
      #pragma unroll
      for (int r = 0; r < 4; ++r)
        #pragma unroll
        for (int cc = 0; cc < 4; ++cc) {
          accq[r][cc] = fmaf(a[r], b[cc], accq[r][cc]);
          acck[r][cc] = fmaf(a[r], c[cc], acck[r][cc]);
        }
    }
  }
  float4 bq4 = *(const float4*)(bqv + i0 + tx*4);
  float4 bk4 = *(const float4*)(bkv + i0 + tx*4);
  #pragma unroll
  for (int r = 0; r < 4; ++r) {
    int trow = t0 + ty*4 + r;
    float4 oq = { accq[r][0]+bq4.x, accq[r][1]+bq4.y, accq[r][2]+bq4.z, accq[r][3]+bq4.w };
    float4 ok = { acck[r][0]+bk4.x, acck[r][1]+bk4.y, acck[r][2]+bk4.z, acck[r][3]+bk4.w };
    *(float4*)(qout + (size_t)trow * D + i0 + tx*4) = oq;
    *(float4*)(kout + (size_t)trow * D + i0 + tx*4) = ok;
  }
}

__global__ __launch_bounds__(256) void attn_kernel(
    const float* __restrict__ x, const float* __restrict__ q,
    const float* __restrict__ kmat, const float* __restrict__ xsum,
    float* __restrict__ out)
{
  __shared__ __align__(16) float scl[TQ][UMAX];
  __shared__ float e0s[TQ], dinv[TQ];
  const int tid = threadIdx.x, lane = tid & 63, wv = tid >> 6;
  const int t0 = blockIdx.x * TQ;
  const int lo_u = max(0, t0 - WINDOW);
  const int hi_u = min(S, t0 + TQ - 1 + WINDOW);
  const int ucnt = hi_u - lo_u;
  for (int i = tid; i < TQ * UMAX; i += 256) (&scl[0][0])[i] = 0.f;
  __syncthreads();
  {
    const int tiB = wv * 4;
    float4 qf[4][4];
    #pragma unroll
    for (int g = 0; g < 4; ++g) {
      int t = t0 + tiB + g;
      #pragma unroll
      for (int j = 0; j < 4; ++j)
        qf[g][j] = *(const float4*)(q + (size_t)t * D + lane*4 + j*256);
    }
    const int wlo = max(0, t0 + tiB - WINDOW);
    const int whi = min(S, t0 + tiB + 3 + WINDOW);
    for (int s = wlo; s < whi; ++s) {
      float4 kf[4];
      #pragma unroll
      for (int j = 0; j < 4; ++j)
        kf[j] = *(const float4*)(kmat + (size_t)s * D + lane*4 + j*256);
      float acc[4];
      #pragma unroll
      for (int g = 0; g < 4; ++g) {
        float v = 0.f;
        #pragma unroll
        for (int j = 0; j < 4; ++j) {
          v = fmaf(qf[g][j].x, kf[j].x, v);
          v = fmaf(qf[g][j].y, kf[j].y, v);
          v = fmaf(qf[g][j].z, kf[j].z, v);
          v = fmaf(qf[g][j].w, kf[j].w, v);
        }
        acc[g] = v;
      }
      #pragma unroll
      for (int g = 0; g < 4; ++g) {
        float tot = wave_sum(acc[g]);
        int t = t0 + tiB + g;
        if (lane == 0 && s >= t - WINDOW && s < t + WINDOW)
          scl[tiB + g][s - lo_u] = tot;
      }
    }
  }
  __syncthreads();
  #pragma unroll
  for (int g = 0; g < 4; ++g) {
    int ti = wv * 4 + g;
    int t = t0 + ti;
    int lo = max(0, t - WINDOW), hi = min(S, t + WINDOW);
    int cnt = hi - lo, off = lo - lo_u;
    float m = 0.f;
    for (int i = lane; i < cnt; i += 64) m = fmaxf(m, scl[ti][off + i]);
    m = wave_max(m);
    float e0 = __expf(-m);
    float ssum = 0.f;
    for (int i = lane; i < cnt; i += 64) {
      float e = __expf(scl[ti][off + i] - m);
      ssum += e;
      scl[ti][off + i] = e - e0;
    }
    ssum = wave_sum(ssum);
    if (lane == 0) {
      dinv[ti] = 1.f / (ssum + (float)(S - cnt) * e0);
      e0s[ti] = e0;
    }
  }
  __syncthreads();
  {
    const int c4 = tid * 4;
    float4 acc[TQ];
    #pragma unroll
    for (int ti = 0; ti < TQ; ++ti) acc[ti] = make_float4(0.f, 0.f, 0.f, 0.f);
    for (int su = 0; su < ucnt; su += 4) {
      float4 xr[4];
      #pragma unroll
      for (int u = 0; u < 4; ++u)
        xr[u] = *(const float4*)(x + (size_t)(lo_u + su + u) * D + c4);
      #pragma unroll
      for (int ti = 0; ti < TQ; ++ti) {
        float4 w4 = *(const float4*)&scl[ti][su];
        float wvv[4] = {w4.x, w4.y, w4.z, w4.w};
        #pragma unroll
        for (int u = 0; u < 4; ++u) {
          acc[ti].x = fmaf(wvv[u], xr[u].x, acc[ti].x);
          acc[ti].y = fmaf(wvv[u], xr[u].y, acc[ti].y);
          acc[ti].z = fmaf(wvv[u], xr[u].z, acc[ti].z);
          acc[ti].w = fmaf(wvv[u], xr[u].w, acc[ti].w);
        }
      }
    }
    float4 xsv = *(const float4*)(xsum + c4);
    #pragma unroll
    for (int ti = 0; ti < TQ; ++ti) {
      float e0 = e0s[ti], di = dinv[ti];
      float4 o;
      o.x = (acc[ti].x + e0 * xsv.x) * di;
      o.y = (acc[ti].y + e0 * xsv.y) * di;
      o.z = (acc[ti].z + e0 * xsv.z) * di;
      o.w = (acc[ti].w + e0 * xsv.w) * di;
      *(float4*)(out + (size_t)(t0 + ti) * D + c4) = o;
    }
  }
}

extern "C" void kernel_launch(void* const* d_in, const int* in_sizes, int n_in,
                              void* d_out, int out_size, void* d_ws, size_t ws_size,
                              hipStream_t stream) {
  const float* x  = (const float*)d_in[0];
  const float* Wq = (const float*)d_in[1];
  const float* bq = (const float*)d_in[2];
  const float* Wk = (const float*)d_in[3];
  const float* bk = (const float*)d_in[4];
  float* outp = (float*)d_out;

  const size_t SD = (size_t)S * D;
  const size_t DD = (size_t)D * D;

  // workspace layout (identical footprint to round 4)
  float* xsum = (float*)d_ws;                       // 4 KB
  u16t* xhi = (u16t*)(xsum + D);                    // 16 MB
  u16t* xlo = xhi + SD;                             // 16 MB
  u16t* wqh = xlo + SD;
  u16t* wql = wqh + DD;
  u16t* wkh = wql + DD;
  u16t* wkl = wkh + DD;
  u16t* qh  = wkl + DD;
  u16t* ql  = qh + SD;
  u16t* kh  = ql + SD;
  u16t* kl  = kh + SD;
  u16t* xT  = kl + SD;
  size_t needed = (size_t)((char*)(xT + SD) - (char*)d_ws);

  // band buffers alias xhi/xlo (dead after gemm_qk)
  float* band = (float*)xhi;                        // 8192*384*4 = 12.6 MB < 16 MB
  u16t*  Pb   = xlo;                                // 8192*384*2 = 6.3 MB
  float* e0d  = (float*)(Pb + (size_t)S * BAND);    // 32 KB, still inside xlo's 16 MB

  hipMemsetAsync(xsum, 0, D * sizeof(float), stream);
  colsum_kernel<<<dim3(D / 256, S / 256), 256, 0, stream>>>(x, xsum);

  if (ws_size >= needed) {
    split_kernel<<<SD / 1024, 256, 0, stream>>>(x,  xhi, xlo);
    split_kernel<<<DD / 1024, 256, 0, stream>>>(Wq, wqh, wql);
    split_kernel<<<DD / 1024, 256, 0, stream>>>(Wk, wkh, wkl);
    transpose_x<<<dim3(S / 64, D / 64), 256, 0, stream>>>(x, xT);
    gemm_qk<<<dim3(S / 128, D / 128, 2), 256, 0, stream>>>(
        xhi, xlo, wqh, wql, wkh, wkl, bq, bk, qh, ql, kh, kl);
    scores_kernel<<<dim3(S / 128, 3), 256, 0, stream>>>(qh, ql, kh, kl, band);
    softmax_kernel<<<S / 4, 256, 0, stream>>>(band, Pb, e0d);
    pv_kernel<<<dim3(S / 128, D / 128), 256, 0, stream>>>(Pb, xT, e0d, xsum, outp);
  } else {
    float* q    = (float*)(xsum + D);
    float* kbuf = q + SD;
    proj_kernel<<<dim3(S / 64, D / 64), 256, 0, stream>>>(x, Wq, bq, Wk, bk, q, kbuf);
    attn_kernel<<<S / TQ, 256, 0, stream>>>(x, q, kbuf, xsum, outp);
  }
}

// Round 7
// 269.389 us; speedup vs baseline: 3.2996x; 1.1023x over previous
//
#include <hip/hip_runtime.h>

#define S 8192
#define D 1024
#define WINDOW 128
#define TQ 16
#define UMAX 288
#define BK 32
#define PAD 68
#define BAND 384   // band width: s in [t_tile-128, t_tile+256)

typedef __attribute__((ext_vector_type(8))) short short8;
typedef __attribute__((ext_vector_type(4))) float floatx4;
typedef __attribute__((ext_vector_type(4))) unsigned short ushort4v;
typedef unsigned short u16t;

__device__ __forceinline__ float wave_sum(float v) {
  #pragma unroll
  for (int off = 32; off > 0; off >>= 1) v += __shfl_xor(v, off, 64);
  return v;
}
__device__ __forceinline__ float wave_max(float v) {
  #pragma unroll
  for (int off = 32; off > 0; off >>= 1) v = fmaxf(v, __shfl_xor(v, off, 64));
  return v;
}
__device__ __forceinline__ unsigned int f2bf_rn(float f) {
  unsigned int u = __float_as_uint(f);
  return (u + 0x7fffu + ((u >> 16) & 1u)) >> 16;
}

// ---------------------------------------------------------------------------
// u[i] = sum_n Wq[n][i]*bk[n] ; v[i] = sum_n Wk[n][i]*bq[n] ; c = bq.bk
// ---------------------------------------------------------------------------
__global__ __launch_bounds__(256) void uv_kernel(
    const float* __restrict__ Wq, const float* __restrict__ Wk,
    const float* __restrict__ bq, const float* __restrict__ bk,
    float* __restrict__ u, float* __restrict__ v, float* __restrict__ cbuf)
{
  const int i = blockIdx.x * 256 + threadIdx.x;
  const int n0 = blockIdx.y * 128;
  float us = 0.f, vs = 0.f;
  for (int n = n0; n < n0 + 128; ++n) {
    us += Wq[(size_t)n * D + i] * bk[n];
    vs += Wk[(size_t)n * D + i] * bq[n];
  }
  atomicAdd(&u[i], us);
  atomicAdd(&v[i], vs);
  if (blockIdx.x == 0 && blockIdx.y == 0) {
    float cs = 0.f;
    for (int n = threadIdx.x; n < D; n += 256) cs += bq[n] * bk[n];
    atomicAdd(cbuf, cs);
  }
}

// ---------------------------------------------------------------------------
// prep: read x tile once -> xhi/xlo (split), xT (bf16 transpose),
//       xsum partials, a = x.u partials, b = x.v partials
// ---------------------------------------------------------------------------
__global__ __launch_bounds__(256) void prep_kernel(
    const float* __restrict__ x, const float* __restrict__ u,
    const float* __restrict__ v, u16t* __restrict__ xhi, u16t* __restrict__ xlo,
    u16t* __restrict__ xT, float* __restrict__ xsum,
    float* __restrict__ a, float* __restrict__ b)
{
  __shared__ float tile[64][65];
  const int s0 = blockIdx.x * 64;
  const int d0 = blockIdx.y * 64;
  const int t = threadIdx.x;
  #pragma unroll
  for (int p = 0; p < 4; ++p) {
    int r = (t >> 4) + p * 16;
    int c = (t & 15) * 4;
    float4 vv = *(const float4*)(x + (size_t)(s0 + r) * D + d0 + c);
    float f[4] = {vv.x, vv.y, vv.z, vv.w};
    tile[r][c+0] = vv.x; tile[r][c+1] = vv.y; tile[r][c+2] = vv.z; tile[r][c+3] = vv.w;
    ushort4v h, l;
    #pragma unroll
    for (int e = 0; e < 4; ++e) {
      unsigned int hb = f2bf_rn(f[e]);
      float hf = __uint_as_float(hb << 16);
      h[e] = (u16t)hb;
      l[e] = (u16t)f2bf_rn(f[e] - hf);
    }
    size_t idx = (size_t)(s0 + r) * D + d0 + c;
    *(ushort4v*)(xhi + idx) = h;
    *(ushort4v*)(xlo + idx) = l;
  }
  __syncthreads();
  // transpose write
  #pragma unroll
  for (int p = 0; p < 4; ++p) {
    int dd = (t >> 4) + p * 16;
    int ss = (t & 15) * 4;
    ushort4v o;
    #pragma unroll
    for (int e = 0; e < 4; ++e) o[e] = (u16t)f2bf_rn(tile[ss + e][dd]);
    *(ushort4v*)(xT + (size_t)(d0 + dd) * S + s0 + ss) = o;
  }
  // reductions
  if (t < 64) {               // column sums -> xsum[d0+t]
    float s = 0.f;
    #pragma unroll 8
    for (int r = 0; r < 64; ++r) s += tile[r][t];
    atomicAdd(&xsum[d0 + t], s);
  } else if (t < 128) {       // a rows
    int r = t - 64;
    float s = 0.f;
    for (int c = 0; c < 64; ++c) s += tile[r][c] * u[d0 + c];
    atomicAdd(&a[s0 + r], s);
  } else if (t < 192) {       // b rows
    int r = t - 128;
    float s = 0.f;
    for (int c = 0; c < 64; ++c) s += tile[r][c] * v[d0 + c];
    atomicAdd(&b[s0 + r], s);
  }
}

// ---------------------------------------------------------------------------
// W fp32 [D][D] -> transposed bf16 hi/lo [D][D] (z=0: Wq, z=1: Wk)
// ---------------------------------------------------------------------------
__global__ __launch_bounds__(256) void transposeW_kernel(
    const float* __restrict__ Wq, const float* __restrict__ Wk,
    u16t* __restrict__ wqth, u16t* __restrict__ wqtl,
    u16t* __restrict__ wkth, u16t* __restrict__ wktl)
{
  __shared__ float tile[64][65];
  const float* W = blockIdx.z ? Wk : Wq;
  u16t* oh = blockIdx.z ? wkth : wqth;
  u16t* ol = blockIdx.z ? wktl : wqtl;
  const int n0 = blockIdx.x * 64;   // source row
  const int i0 = blockIdx.y * 64;   // source col
  const int t = threadIdx.x;
  #pragma unroll
  for (int p = 0; p < 4; ++p) {
    int r = (t >> 4) + p * 16;
    int c = (t & 15) * 4;
    float4 vv = *(const float4*)(W + (size_t)(n0 + r) * D + i0 + c);
    tile[r][c+0] = vv.x; tile[r][c+1] = vv.y; tile[r][c+2] = vv.z; tile[r][c+3] = vv.w;
  }
  __syncthreads();
  #pragma unroll
  for (int p = 0; p < 4; ++p) {
    int ii = (t >> 4) + p * 16;
    int nn = (t & 15) * 4;
    ushort4v h, l;
    #pragma unroll
    for (int e = 0; e < 4; ++e) {
      float f = tile[nn + e][ii];
      unsigned int hb = f2bf_rn(f);
      float hf = __uint_as_float(hb << 16);
      h[e] = (u16t)hb;
      l[e] = (u16t)f2bf_rn(f - hf);
    }
    size_t idx = (size_t)(i0 + ii) * D + n0 + nn;
    *(ushort4v*)(oh + idx) = h;
    *(ushort4v*)(ol + idx) = l;
  }
}

// ---------------------------------------------------------------------------
// M[i][j] = sum_n Wq[n][i]Wk[n][j] = sum WqT[i][n]*WkT[j][n]; hi/lo 3-term.
// 64x64 tile, grid (16,16). Single indexed LDS array (no pointer tables).
// ---------------------------------------------------------------------------
__global__ __launch_bounds__(256) void m_kernel(
    const u16t* __restrict__ wqth, const u16t* __restrict__ wqtl,
    const u16t* __restrict__ wkth, const u16t* __restrict__ wktl,
    u16t* __restrict__ mh, u16t* __restrict__ ml)
{
  __shared__ __align__(16) u16t Mbuf[4][64 * BK];  // 0:Ah 1:Al 2:Bh 3:Bl

  const int tid  = threadIdx.x;
  const int lane = tid & 63;
  const int wv   = tid >> 6;
  const int i0   = blockIdx.x * 64;
  const int j0   = blockIdx.y * 64;

  floatx4 acc[2][2] = {};
  const int m0w = (wv & 1) * 32;
  const int n0w = (wv >> 1) * 32;
  const int srow = lane >> 2;
  const int scol = (lane & 3) * 8;

  for (int k0 = 0; k0 < D; k0 += BK) {
    __syncthreads();
    {
      const u16t* src = (wv == 0) ? wqth : (wv == 1) ? wqtl : (wv == 2) ? wkth : wktl;
      const int base  = (wv < 2) ? i0 : j0;
      #pragma unroll
      for (int sg = 0; sg < 4; ++sg) {
        int row = base + sg * 16 + srow;
        size_t g = (size_t)row * D + k0 + scol;
        __builtin_amdgcn_global_load_lds(
            (const __attribute__((address_space(1))) void*)(src + g),
            (__attribute__((address_space(3))) void*)(&Mbuf[wv][sg * 512]), 16, 0, 0);
      }
    }
    __syncthreads();
    short8 ah[2], al[2], bh[2], bl[2];
    #pragma unroll
    for (int t = 0; t < 2; ++t) {
      int ar = (m0w + t * 16 + (lane & 15)) * BK + (lane >> 4) * 8;
      int br = (n0w + t * 16 + (lane & 15)) * BK + (lane >> 4) * 8;
      ah[t] = *(const short8*)&Mbuf[0][ar];
      al[t] = *(const short8*)&Mbuf[1][ar];
      bh[t] = *(const short8*)&Mbuf[2][br];
      bl[t] = *(const short8*)&Mbuf[3][br];
    }
    #pragma unroll
    for (int mt = 0; mt < 2; ++mt)
      #pragma unroll
      for (int nt = 0; nt < 2; ++nt) {
        acc[mt][nt] = __builtin_amdgcn_mfma_f32_16x16x32_bf16(ah[mt], bh[nt], acc[mt][nt], 0, 0, 0);
        acc[mt][nt] = __builtin_amdgcn_mfma_f32_16x16x32_bf16(ah[mt], bl[nt], acc[mt][nt], 0, 0, 0);
        acc[mt][nt] = __builtin_amdgcn_mfma_f32_16x16x32_bf16(al[mt], bh[nt], acc[mt][nt], 0, 0, 0);
      }
  }
  #pragma unroll
  for (int mt = 0; mt < 2; ++mt)
    #pragma unroll
    for (int nt = 0; nt < 2; ++nt) {
      int j = j0 + n0w + nt * 16 + (lane & 15);
      int i = i0 + m0w + mt * 16 + (lane >> 4) * 4;
      #pragma unroll
      for (int r = 0; r < 4; ++r) {
        float f = acc[mt][nt][r];
        unsigned int hb = f2bf_rn(f);
        float hf = __uint_as_float(hb << 16);
        size_t idx = (size_t)(i + r) * D + j;
        mh[idx] = (u16t)hb;
        ml[idx] = (u16t)f2bf_rn(f - hf);
      }
    }
}

// ---------------------------------------------------------------------------
// Y[s][i] = sum_j x[s][j]*M[i][j]; hi/lo 3-term; epilogue splits -> Yh/Yl.
// ---------------------------------------------------------------------------
__global__ __launch_bounds__(256) void y_kernel(
    const u16t* __restrict__ xhi, const u16t* __restrict__ xlo,
    const u16t* __restrict__ mhp, const u16t* __restrict__ mlp,
    u16t* __restrict__ yh, u16t* __restrict__ yl)
{
  __shared__ __align__(16) u16t Ah[128 * BK];
  __shared__ __align__(16) u16t Al[128 * BK];
  __shared__ __align__(16) u16t Bh[128 * BK];
  __shared__ __align__(16) u16t Bl[128 * BK];

  const int tid  = threadIdx.x;
  const int lane = tid & 63;
  const int wv   = tid >> 6;
  const int s0   = blockIdx.x * 128;
  const int i0   = blockIdx.y * 128;

  floatx4 acc[4][4] = {};
  const int m0w  = (wv & 1) * 64;
  const int n0w  = (wv >> 1) * 64;
  const int srow = lane >> 2;
  const int scol = (lane & 3) * 8;

  for (int k0 = 0; k0 < D; k0 += BK) {
    __syncthreads();
    #pragma unroll
    for (int sg = 0; sg < 2; ++sg) {
      int seg  = wv * 2 + sg;
      int arow = s0 + seg * 16 + srow;
      int brow = i0 + seg * 16 + srow;
      size_t ga = (size_t)arow * D + k0 + scol;
      size_t gb = (size_t)brow * D + k0 + scol;
      __builtin_amdgcn_global_load_lds(
          (const __attribute__((address_space(1))) void*)(xhi + ga),
          (__attribute__((address_space(3))) void*)(&Ah[seg * 512]), 16, 0, 0);
      __builtin_amdgcn_global_load_lds(
          (const __attribute__((address_space(1))) void*)(xlo + ga),
          (__attribute__((address_space(3))) void*)(&Al[seg * 512]), 16, 0, 0);
      __builtin_amdgcn_global_load_lds(
          (const __attribute__((address_space(1))) void*)(mhp + gb),
          (__attribute__((address_space(3))) void*)(&Bh[seg * 512]), 16, 0, 0);
      __builtin_amdgcn_global_load_lds(
          (const __attribute__((address_space(1))) void*)(mlp + gb),
          (__attribute__((address_space(3))) void*)(&Bl[seg * 512]), 16, 0, 0);
    }
    __syncthreads();
    short8 ah[4], al[4], bh[4], bl[4];
    #pragma unroll
    for (int t = 0; t < 4; ++t) {
      int ar = (m0w + t * 16 + (lane & 15)) * BK + (lane >> 4) * 8;
      int br = (n0w + t * 16 + (lane & 15)) * BK + (lane >> 4) * 8;
      ah[t] = *(const short8*)&Ah[ar];
      al[t] = *(const short8*)&Al[ar];
      bh[t] = *(const short8*)&Bh[br];
      bl[t] = *(const short8*)&Bl[br];
    }
    #pragma unroll
    for (int mt = 0; mt < 4; ++mt)
      #pragma unroll
      for (int nt = 0; nt < 4; ++nt) {
        acc[mt][nt] = __builtin_amdgcn_mfma_f32_16x16x32_bf16(ah[mt], bh[nt], acc[mt][nt], 0, 0, 0);
        acc[mt][nt] = __builtin_amdgcn_mfma_f32_16x16x32_bf16(ah[mt], bl[nt], acc[mt][nt], 0, 0, 0);
        acc[mt][nt] = __builtin_amdgcn_mfma_f32_16x16x32_bf16(al[mt], bh[nt], acc[mt][nt], 0, 0, 0);
      }
  }
  #pragma unroll
  for (int mt = 0; mt < 4; ++mt)
    #pragma unroll
    for (int nt = 0; nt < 4; ++nt) {
      int i = i0 + n0w + nt * 16 + (lane & 15);
      int s = s0 + m0w + mt * 16 + (lane >> 4) * 4;
      #pragma unroll
      for (int r = 0; r < 4; ++r) {
        float f = acc[mt][nt][r];
        unsigned int hb = f2bf_rn(f);
        float hf = __uint_as_float(hb << 16);
        size_t idx = (size_t)(s + r) * D + i;
        yh[idx] = (u16t)hb;
        yl[idx] = (u16t)f2bf_rn(f - hf);
      }
    }
}

// ---------------------------------------------------------------------------
// Banded scores: band[t][j] = x_t.Y_s + a[t] + b[s] + c  (s = t0-128+j),
// window-masked (else 0). grid (S/128, 3).
// ---------------------------------------------------------------------------
__global__ __launch_bounds__(256) void scores_kernel(
    const u16t* __restrict__ xhi, const u16t* __restrict__ xlo,
    const u16t* __restrict__ yh, const u16t* __restrict__ yl,
    const float* __restrict__ a, const float* __restrict__ b,
    const float* __restrict__ cbuf, float* __restrict__ band)
{
  __shared__ __align__(16) u16t Ah[128 * BK];
  __shared__ __align__(16) u16t Al[128 * BK];
  __shared__ __align__(16) u16t Bh[128 * BK];
  __shared__ __align__(16) u16t Bl[128 * BK];

  const int tid  = threadIdx.x;
  const int lane = tid & 63;
  const int wv   = tid >> 6;
  const int t0   = blockIdx.x * 128;
  const int jt   = blockIdx.y;
  const int s_base = t0 - 128 + jt * 128;
  const float cval = cbuf[0];

  floatx4 acc[4][4] = {};
  const int m0w  = (wv & 1) * 64;
  const int n0w  = (wv >> 1) * 64;
  const int srow = lane >> 2;
  const int scol = (lane & 3) * 8;

  for (int k0 = 0; k0 < D; k0 += BK) {
    __syncthreads();
    #pragma unroll
    for (int sg = 0; sg < 2; ++sg) {
      int seg  = wv * 2 + sg;
      int arow = t0 + seg * 16 + srow;
      int brow = s_base + seg * 16 + srow;
      brow = min(max(brow, 0), S - 1);
      size_t ga = (size_t)arow * D + k0 + scol;
      size_t gb = (size_t)brow * D + k0 + scol;
      __builtin_amdgcn_global_load_lds(
          (const __attribute__((address_space(1))) void*)(xhi + ga),
          (__attribute__((address_space(3))) void*)(&Ah[seg * 512]), 16, 0, 0);
      __builtin_amdgcn_global_load_lds(
          (const __attribute__((address_space(1))) void*)(xlo + ga),
          (__attribute__((address_space(3))) void*)(&Al[seg * 512]), 16, 0, 0);
      __builtin_amdgcn_global_load_lds(
          (const __attribute__((address_space(1))) void*)(yh + gb),
          (__attribute__((address_space(3))) void*)(&Bh[seg * 512]), 16, 0, 0);
      __builtin_amdgcn_global_load_lds(
          (const __attribute__((address_space(1))) void*)(yl + gb),
          (__attribute__((address_space(3))) void*)(&Bl[seg * 512]), 16, 0, 0);
    }
    __syncthreads();
    short8 ah[4], al[4], bh[4], bl[4];
    #pragma unroll
    for (int t = 0; t < 4; ++t) {
      int ar = (m0w + t * 16 + (lane & 15)) * BK + (lane >> 4) * 8;
      int br = (n0w + t * 16 + (lane & 15)) * BK + (lane >> 4) * 8;
      ah[t] = *(const short8*)&Ah[ar];
      al[t] = *(const short8*)&Al[ar];
      bh[t] = *(const short8*)&Bh[br];
      bl[t] = *(const short8*)&Bl[br];
    }
    #pragma unroll
    for (int mt = 0; mt < 4; ++mt)
      #pragma unroll
      for (int nt = 0; nt < 4; ++nt) {
        acc[mt][nt] = __builtin_amdgcn_mfma_f32_16x16x32_bf16(ah[mt], bh[nt], acc[mt][nt], 0, 0, 0);
        acc[mt][nt] = __builtin_amdgcn_mfma_f32_16x16x32_bf16(ah[mt], bl[nt], acc[mt][nt], 0, 0, 0);
        acc[mt][nt] = __builtin_amdgcn_mfma_f32_16x16x32_bf16(al[mt], bh[nt], acc[mt][nt], 0, 0, 0);
      }
  }
  #pragma unroll
  for (int mt = 0; mt < 4; ++mt)
    #pragma unroll
    for (int nt = 0; nt < 4; ++nt) {
      int n_loc = n0w + nt * 16 + (lane & 15);
      int s = s_base + n_loc;
      float bv = (s >= 0 && s < S) ? b[s] : 0.f;
      #pragma unroll
      for (int r = 0; r < 4; ++r) {
        int m_loc = m0w + mt * 16 + (lane >> 4) * 4 + r;
        int t = t0 + m_loc;
        bool inwin = (s >= t - WINDOW) && (s < t + WINDOW) && (s >= 0) && (s < S);
        float sv = inwin ? (acc[mt][nt][r] + a[t] + bv + cval) : 0.f;
        band[(size_t)t * BAND + jt * 128 + n_loc] = sv;
      }
    }
}

// ---------------------------------------------------------------------------
// Softmax over band; P = (e - e0)*dinv as bf16; e0d = e0*dinv.
// ---------------------------------------------------------------------------
__global__ __launch_bounds__(256) void softmax_kernel(
    const float* __restrict__ band, u16t* __restrict__ Pb, float* __restrict__ e0d)
{
  const int lane = threadIdx.x & 63;
  const int w    = threadIdx.x >> 6;
  const int t    = blockIdx.x * 4 + w;
  const float* row = band + (size_t)t * BAND;
  float v[6];
  float mx = 0.f;
  #pragma unroll
  for (int i = 0; i < 6; ++i) {
    v[i] = row[i * 64 + lane];
    mx = fmaxf(mx, v[i]);
  }
  mx = wave_max(mx);
  float e0 = __expf(-mx);
  float ss = 0.f;
  #pragma unroll
  for (int i = 0; i < 6; ++i) {
    v[i] = __expf(v[i] - mx);
    ss += v[i];
  }
  ss = wave_sum(ss);
  float dinv = 1.f / (ss + (float)(S - BAND) * e0);
  #pragma unroll
  for (int i = 0; i < 6; ++i)
    Pb[(size_t)t * BAND + i * 64 + lane] = (u16t)f2bf_rn((v[i] - e0) * dinv);
  if (lane == 0) e0d[t] = e0 * dinv;
}

// ---------------------------------------------------------------------------
// PV: out[t][d] = sum_j Pb[t][j]*x[origin+j][d] + e0d[t]*xsum[d].
// ---------------------------------------------------------------------------
__global__ __launch_bounds__(256) void pv_kernel(
    const u16t* __restrict__ Pb, const u16t* __restrict__ xT,
    const float* __restrict__ e0d, const float* __restrict__ xsum,
    float* __restrict__ out)
{
  __shared__ __align__(16) u16t Ab[128 * BK];
  __shared__ __align__(16) u16t Bb[128 * BK];

  const int tid  = threadIdx.x;
  const int lane = tid & 63;
  const int wv   = tid >> 6;
  const int t0   = blockIdx.x * 128;
  const int d0   = blockIdx.y * 128;
  const int origin = t0 - 128;

  floatx4 acc[4][4] = {};
  const int m0w  = (wv & 1) * 64;
  const int n0w  = (wv >> 1) * 64;
  const int srow = lane >> 2;
  const int scol = (lane & 3) * 8;

  for (int k0 = 0; k0 < BAND; k0 += BK) {
    __syncthreads();
    #pragma unroll
    for (int sg = 0; sg < 2; ++sg) {
      int seg  = wv * 2 + sg;
      int arow = t0 + seg * 16 + srow;
      int brow = d0 + seg * 16 + srow;
      int s_g  = origin + k0 + scol;
      s_g = min(max(s_g, 0), S - 8);
      size_t ga = (size_t)arow * BAND + k0 + scol;
      size_t gb = (size_t)brow * S + s_g;
      __builtin_amdgcn_global_load_lds(
          (const __attribute__((address_space(1))) void*)(Pb + ga),
          (__attribute__((address_space(3))) void*)(&Ab[seg * 512]), 16, 0, 0);
      __builtin_amdgcn_global_load_lds(
          (const __attribute__((address_space(1))) void*)(xT + gb),
          (__attribute__((address_space(3))) void*)(&Bb[seg * 512]), 16, 0, 0);
    }
    __syncthreads();
    short8 af[4], bf[4];
    #pragma unroll
    for (int t = 0; t < 4; ++t) {
      int ar = (m0w + t * 16 + (lane & 15)) * BK + (lane >> 4) * 8;
      int br = (n0w + t * 16 + (lane & 15)) * BK + (lane >> 4) * 8;
      af[t] = *(const short8*)&Ab[ar];
      bf[t] = *(const short8*)&Bb[br];
    }
    #pragma unroll
    for (int mt = 0; mt < 4; ++mt)
      #pragma unroll
      for (int nt = 0; nt < 4; ++nt)
        acc[mt][nt] = __builtin_amdgcn_mfma_f32_16x16x32_bf16(af[mt], bf[nt], acc[mt][nt], 0, 0, 0);
  }
  #pragma unroll
  for (int mt = 0; mt < 4; ++mt)
    #pragma unroll
    for (int nt = 0; nt < 4; ++nt) {
      int n_g = d0 + n0w + nt * 16 + (lane & 15);
      float xs = xsum[n_g];
      #pragma unroll
      for (int r = 0; r < 4; ++r) {
        int m_g = t0 + m0w + mt * 16 + (lane >> 4) * 4 + r;
        out[(size_t)m_g * D + n_g] = acc[mt][nt][r] + e0d[m_g] * xs;
      }
    }
}

// ---------------------------------------------------------------------------
// Fallback path (round-3 verified): fp32 proj + VALU attn
// ---------------------------------------------------------------------------
__global__ __launch_bounds__(256) void proj_kernel(
    const float* __restrict__ x, const float* __restrict__ Wq,
    const float* __restrict__ bqv, const float* __restrict__ Wk,
    const float* __restrict__ bkv, float* __restrict__ qout,
    float* __restrict__ kout)
{
  __shared__ __align__(16) float xs[BK][PAD];
  __shared__ __align__(16) float wqs[BK][PAD];
  __shared__ __align__(16) float wks[BK][PAD];
  const int tid = threadIdx.x;
  const int tx = tid & 15, ty = tid >> 4;
  const int t0 = blockIdx.x * 64, i0 = blockIdx.y * 64;
  float accq[4][4] = {}, acck[4][4] = {};
  const int lrow0 = tid >> 3, lc4 = (tid & 7) * 4;
  for (int k0 = 0; k0 < D; k0 += BK) {
    __syncthreads();
    #pragma unroll
    for (int p = 0; p < 2; ++p) {
      int row = lrow0 + p * 32;
      float4 a = *(const float4*)(x  + (size_t)(t0 + row) * D + k0 + lc4);
      float4 b = *(const float4*)(Wq + (size_t)(i0 + row) * D + k0 + lc4);
      float4 c = *(const float4*)(Wk + (size_t)(i0 + row) * D + k0 + lc4);
      xs [lc4+0][row]=a.x; xs [lc4+1][row]=a.y; xs [lc4+2][row]=a.z; xs [lc4+3][row]=a.w;
      wqs[lc4+0][row]=b.x; wqs[lc4+1][row]=b.y; wqs[lc4+2][row]=b.z; wqs[lc4+3][row]=b.w;
      wks[lc4+0][row]=c.x; wks[lc4+1][row]=c.y; wks[lc4+2][row]=c.z; wks[lc4+3][row]=c.w;
    }
    __syncthreads();
    #pragma unroll
    for (int kk = 0; kk < BK; ++kk) {
      float4 av = *(const float4*)&xs [kk][ty*4];
      float4 bv = *(const float4*)&wqs[kk][tx*4];
      float4 cv = *(const float4*)&wks[kk][tx*4];
      float a[4] = {av.x, av.y, av.z, av.w};
      float b[4] = {bv.x, bv.y, bv.z, bv.w};
      float c[4] = {cv.x, cv.y, cv.z, cv.w};
      #pragma unroll
      for (int r = 0; r < 4; ++r)
        #pragma unroll
        for (int cc = 0; cc < 4; ++cc) {
          accq[r][cc] = fmaf(a[r], b[cc], accq[r][cc]);
          acck[r][cc] = fmaf(a[r], c[cc], acck[r][cc]);
        }
    }
  }
  float4 bq4 = *(const float4*)(bqv + i0 + tx*4);
  float4 bk4 = *(const float4*)(bkv + i0 + tx*4);
  #pragma unroll
  for (int r = 0; r < 4; ++r) {
    int trow = t0 + ty*4 + r;
    float4 oq = { accq[r][0]+bq4.x, accq[r][1]+bq4.y, accq[r][2]+bq4.z, accq[r][3]+bq4.w };
    float4 ok = { acck[r][0]+bk4.x, acck[r][1]+bk4.y, acck[r][2]+bk4.z, acck[r][3]+bk4.w };
    *(float4*)(qout + (size_t)trow * D + i0 + tx*4) = oq;
    *(float4*)(kout + (size_t)trow * D + i0 + tx*4) = ok;
  }
}

__global__ __launch_bounds__(256) void colsum_kernel(const float* __restrict__ x,
                                                     float* __restrict__ xsum)
{
  int d = blockIdx.x * 256 + threadIdx.x;
  int tbase = blockIdx.y * 256;
  float s = 0.f;
  for (int t = 0; t < 256; ++t) s += x[(size_t)(tbase + t) * D + d];
  atomicAdd(&xsum[d], s);
}

__global__ __launch_bounds__(256) void attn_kernel(
    const float* __restrict__ x, const float* __restrict__ q,
    const float* __restrict__ kmat, const float* __restrict__ xsum,
    float* __restrict__ out)
{
  __shared__ __align__(16) float scl[TQ][UMAX];
  __shared__ float e0s[TQ], dinv[TQ];
  const int tid = threadIdx.x, lane = tid & 63, wv = tid >> 6;
  const int t0 = blockIdx.x * TQ;
  const int lo_u = max(0, t0 - WINDOW);
  const int hi_u = min(S, t0 + TQ - 1 + WINDOW);
  const int ucnt = hi_u - lo_u;
  for (int i = tid; i < TQ * UMAX; i += 256) (&scl[0][0])[i] = 0.f;
  __syncthreads();
  {
    const int tiB = wv * 4;
    float4 qf[4][4];
    #pragma unroll
    for (int g = 0; g < 4; ++g) {
      int t = t0 + tiB + g;
      #pragma unroll
      for (int j = 0; j < 4; ++j)
        qf[g][j] = *(const float4*)(q + (size_t)t * D + lane*4 + j*256);
    }
    const int wlo = max(0, t0 + tiB - WINDOW);
    const int whi = min(S, t0 + tiB + 3 + WINDOW);
    for (int s = wlo; s < whi; ++s) {
      float4 kf[4];
      #pragma unroll
      for (int j = 0; j < 4; ++j)
        kf[j] = *(const float4*)(kmat + (size_t)s * D + lane*4 + j*256);
      float acc[4];
      #pragma unroll
      for (int g = 0; g < 4; ++g) {
        float v = 0.f;
        #pragma unroll
        for (int j = 0; j < 4; ++j) {
          v = fmaf(qf[g][j].x, kf[j].x, v);
          v = fmaf(qf[g][j].y, kf[j].y, v);
          v = fmaf(qf[g][j].z, kf[j].z, v);
          v = fmaf(qf[g][j].w, kf[j].w, v);
        }
        acc[g] = v;
      }
      #pragma unroll
      for (int g = 0; g < 4; ++g) {
        float tot = wave_sum(acc[g]);
        int t = t0 + tiB + g;
        if (lane == 0 && s >= t - WINDOW && s < t + WINDOW)
          scl[tiB + g][s - lo_u] = tot;
      }
    }
  }
  __syncthreads();
  #pragma unroll
  for (int g = 0; g < 4; ++g) {
    int ti = wv * 4 + g;
    int t = t0 + ti;
    int lo = max(0, t - WINDOW), hi = min(S, t + WINDOW);
    int cnt = hi - lo, off = lo - lo_u;
    float m = 0.f;
    for (int i = lane; i < cnt; i += 64) m = fmaxf(m, scl[ti][off + i]);
    m = wave_max(m);
    float e0 = __expf(-m);
    float ssum = 0.f;
    for (int i = lane; i < cnt; i += 64) {
      float e = __expf(scl[ti][off + i] - m);
      ssum += e;
      scl[ti][off + i] = e - e0;
    }
    ssum = wave_sum(ssum);
    if (lane == 0) {
      dinv[ti] = 1.f / (ssum + (float)(S - cnt) * e0);
      e0s[ti] = e0;
    }
  }
  __syncthreads();
  {
    const int c4 = tid * 4;
    float4 acc[TQ];
    #pragma unroll
    for (int ti = 0; ti < TQ; ++ti) acc[ti] = make_float4(0.f, 0.f, 0.f, 0.f);
    for (int su = 0; su < ucnt; su += 4) {
      float4 xr[4];
      #pragma unroll
      for (int u = 0; u < 4; ++u)
        xr[u] = *(const float4*)(x + (size_t)(lo_u + su + u) * D + c4);
      #pragma unroll
      for (int ti = 0; ti < TQ; ++ti) {
        float4 w4 = *(const float4*)&scl[ti][su];
        float wvv[4] = {w4.x, w4.y, w4.z, w4.w};
        #pragma unroll
        for (int u = 0; u < 4; ++u) {
          acc[ti].x = fmaf(wvv[u], xr[u].x, acc[ti].x);
          acc[ti].y = fmaf(wvv[u], xr[u].y, acc[ti].y);
          acc[ti].z = fmaf(wvv[u], xr[u].z, acc[ti].z);
          acc[ti].w = fmaf(wvv[u], xr[u].w, acc[ti].w);
        }
      }
    }
    float4 xsv = *(const float4*)(xsum + c4);
    #pragma unroll
    for (int ti = 0; ti < TQ; ++ti) {
      float e0 = e0s[ti], di = dinv[ti];
      float4 o;
      o.x = (acc[ti].x + e0 * xsv.x) * di;
      o.y = (acc[ti].y + e0 * xsv.y) * di;
      o.z = (acc[ti].z + e0 * xsv.z) * di;
      o.w = (acc[ti].w + e0 * xsv.w) * di;
      *(float4*)(out + (size_t)(t0 + ti) * D + c4) = o;
    }
  }
}

extern "C" void kernel_launch(void* const* d_in, const int* in_sizes, int n_in,
                              void* d_out, int out_size, void* d_ws, size_t ws_size,
                              hipStream_t stream) {
  const float* x  = (const float*)d_in[0];
  const float* Wq = (const float*)d_in[1];
  const float* bq = (const float*)d_in[2];
  const float* Wk = (const float*)d_in[3];
  const float* bk = (const float*)d_in[4];
  float* outp = (float*)d_out;

  const size_t SD = (size_t)S * D;
  const size_t DD = (size_t)D * D;

  // fp32 scalar region (zeroed by one memset)
  float* xsum = (float*)d_ws;            // D
  float* u    = xsum + D;                // D
  float* v    = u + D;                   // D
  float* a    = v + D;                   // S
  float* b    = a + S;                   // S
  float* cbuf = b + S;                   // 16
  size_t zero_bytes = (size_t)(3 * D + 2 * S + 16) * sizeof(float);

  u16t* xhi  = (u16t*)(cbuf + 16);
  u16t* xlo  = xhi + SD;
  u16t* xT   = xlo + SD;
  u16t* wqth = xT + SD;
  u16t* wqtl = wqth + DD;
  u16t* wkth = wqtl + DD;
  u16t* wktl = wkth + DD;
  u16t* mh   = wktl + DD;
  u16t* ml   = mh + DD;
  u16t* yh   = ml + DD;
  u16t* yl   = yh + SD;
  float* band = (float*)(yl + SD);                // S*BAND f32
  u16t*  Pb   = (u16t*)(band + (size_t)S * BAND); // S*BAND u16
  float* e0d  = (float*)(Pb + (size_t)S * BAND);  // S f32
  size_t needed = (size_t)((char*)(e0d + S) - (char*)d_ws);

  if (ws_size >= needed) {
    (void)hipMemsetAsync(d_ws, 0, zero_bytes, stream);
    uv_kernel<<<dim3(D / 256, 8), 256, 0, stream>>>(Wq, Wk, bq, bk, u, v, cbuf);
    prep_kernel<<<dim3(S / 64, D / 64), 256, 0, stream>>>(x, u, v, xhi, xlo, xT, xsum, a, b);
    transposeW_kernel<<<dim3(D / 64, D / 64, 2), 256, 0, stream>>>(Wq, Wk, wqth, wqtl, wkth, wktl);
    m_kernel<<<dim3(D / 64, D / 64), 256, 0, stream>>>(wqth, wqtl, wkth, wktl, mh, ml);
    y_kernel<<<dim3(S / 128, D / 128), 256, 0, stream>>>(xhi, xlo, mh, ml, yh, yl);
    scores_kernel<<<dim3(S / 128, 3), 256, 0, stream>>>(xhi, xlo, yh, yl, a, b, cbuf, band);
    softmax_kernel<<<S / 4, 256, 0, stream>>>(band, Pb, e0d);
    pv_kernel<<<dim3(S / 128, D / 128), 256, 0, stream>>>(Pb, xT, e0d, xsum, outp);
  } else {
    float* xs2  = (float*)d_ws;
    float* q    = xs2 + D;
    float* kbuf = q + SD;
    (void)hipMemsetAsync(xs2, 0, D * sizeof(float), stream);
    colsum_kernel<<<dim3(D / 256, S / 256), 256, 0, stream>>>(x, xs2);
    proj_kernel<<<dim3(S / 64, D / 64), 256, 0, stream>>>(x, Wq, bq, Wk, bk, q, kbuf);
    attn_kernel<<<S / TQ, 256, 0, stream>>>(x, q, kbuf, xs2, outp);
  }
}

// Round 9
// 260.876 us; speedup vs baseline: 3.4073x; 1.0326x over previous
//
#include <hip/hip_runtime.h>

#define S 8192
#define D 1024
#define WINDOW 128
#define TQ 16
#define UMAX 288
#define BK 32
#define PAD 68
#define BAND 384   // band width: s in [t_tile-128, t_tile+256)

typedef __attribute__((ext_vector_type(8))) short short8;
typedef __attribute__((ext_vector_type(4))) float floatx4;
typedef __attribute__((ext_vector_type(4))) unsigned short ushort4v;
typedef unsigned short u16t;

__device__ __forceinline__ float wave_sum(float v) {
  #pragma unroll
  for (int off = 32; off > 0; off >>= 1) v += __shfl_xor(v, off, 64);
  return v;
}
__device__ __forceinline__ float wave_max(float v) {
  #pragma unroll
  for (int off = 32; off > 0; off >>= 1) v = fmaxf(v, __shfl_xor(v, off, 64));
  return v;
}
__device__ __forceinline__ unsigned int f2bf_rn(float f) {
  unsigned int u = __float_as_uint(f);
  return (u + 0x7fffu + ((u >> 16) & 1u)) >> 16;
}

// ---------------------------------------------------------------------------
// u[i] = sum_n Wq[n][i]*bk[n] ; v[i] = sum_n Wk[n][i]*bq[n] ; c = bq.bk
// ---------------------------------------------------------------------------
__global__ __launch_bounds__(256) void uv_kernel(
    const float* __restrict__ Wq, const float* __restrict__ Wk,
    const float* __restrict__ bq, const float* __restrict__ bk,
    float* __restrict__ u, float* __restrict__ v, float* __restrict__ cbuf)
{
  const int i = blockIdx.x * 256 + threadIdx.x;
  const int n0 = blockIdx.y * 128;
  float us = 0.f, vs = 0.f;
  for (int n = n0; n < n0 + 128; ++n) {
    us += Wq[(size_t)n * D + i] * bk[n];
    vs += Wk[(size_t)n * D + i] * bq[n];
  }
  atomicAdd(&u[i], us);
  atomicAdd(&v[i], vs);
  if (blockIdx.x == 0 && blockIdx.y == 0) {
    float cs = 0.f;
    for (int n = threadIdx.x; n < D; n += 256) cs += bq[n] * bk[n];
    atomicAdd(cbuf, cs);
  }
}

// ---------------------------------------------------------------------------
// prep: read x tile once -> xhi/xlo (split), xT (bf16 transpose),
//       xsum partials, a = x.u partials, b = x.v partials
// ---------------------------------------------------------------------------
__global__ __launch_bounds__(256) void prep_kernel(
    const float* __restrict__ x, const float* __restrict__ u,
    const float* __restrict__ v, u16t* __restrict__ xhi, u16t* __restrict__ xlo,
    u16t* __restrict__ xT, float* __restrict__ xsum,
    float* __restrict__ a, float* __restrict__ b)
{
  __shared__ float tile[64][65];
  const int s0 = blockIdx.x * 64;
  const int d0 = blockIdx.y * 64;
  const int t = threadIdx.x;
  #pragma unroll
  for (int p = 0; p < 4; ++p) {
    int r = (t >> 4) + p * 16;
    int c = (t & 15) * 4;
    float4 vv = *(const float4*)(x + (size_t)(s0 + r) * D + d0 + c);
    float f[4] = {vv.x, vv.y, vv.z, vv.w};
    tile[r][c+0] = vv.x; tile[r][c+1] = vv.y; tile[r][c+2] = vv.z; tile[r][c+3] = vv.w;
    ushort4v h, l;
    #pragma unroll
    for (int e = 0; e < 4; ++e) {
      unsigned int hb = f2bf_rn(f[e]);
      float hf = __uint_as_float(hb << 16);
      h[e] = (u16t)hb;
      l[e] = (u16t)f2bf_rn(f[e] - hf);
    }
    size_t idx = (size_t)(s0 + r) * D + d0 + c;
    *(ushort4v*)(xhi + idx) = h;
    *(ushort4v*)(xlo + idx) = l;
  }
  __syncthreads();
  // transpose write
  #pragma unroll
  for (int p = 0; p < 4; ++p) {
    int dd = (t >> 4) + p * 16;
    int ss = (t & 15) * 4;
    ushort4v o;
    #pragma unroll
    for (int e = 0; e < 4; ++e) o[e] = (u16t)f2bf_rn(tile[ss + e][dd]);
    *(ushort4v*)(xT + (size_t)(d0 + dd) * S + s0 + ss) = o;
  }
  // reductions
  if (t < 64) {               // column sums -> xsum[d0+t]
    float s = 0.f;
    #pragma unroll 8
    for (int r = 0; r < 64; ++r) s += tile[r][t];
    atomicAdd(&xsum[d0 + t], s);
  } else if (t < 128) {       // a rows
    int r = t - 64;
    float s = 0.f;
    for (int c = 0; c < 64; ++c) s += tile[r][c] * u[d0 + c];
    atomicAdd(&a[s0 + r], s);
  } else if (t < 192) {       // b rows
    int r = t - 128;
    float s = 0.f;
    for (int c = 0; c < 64; ++c) s += tile[r][c] * v[d0 + c];
    atomicAdd(&b[s0 + r], s);
  }
}

// ---------------------------------------------------------------------------
// W fp32 [D][D] -> transposed bf16 hi/lo [D][D] (z=0: Wq, z=1: Wk)
// ---------------------------------------------------------------------------
__global__ __launch_bounds__(256) void transposeW_kernel(
    const float* __restrict__ Wq, const float* __restrict__ Wk,
    u16t* __restrict__ wqth, u16t* __restrict__ wqtl,
    u16t* __restrict__ wkth, u16t* __restrict__ wktl)
{
  __shared__ float tile[64][65];
  const float* W = blockIdx.z ? Wk : Wq;
  u16t* oh = blockIdx.z ? wkth : wqth;
  u16t* ol = blockIdx.z ? wktl : wqtl;
  const int n0 = blockIdx.x * 64;   // source row
  const int i0 = blockIdx.y * 64;   // source col
  const int t = threadIdx.x;
  #pragma unroll
  for (int p = 0; p < 4; ++p) {
    int r = (t >> 4) + p * 16;
    int c = (t & 15) * 4;
    float4 vv = *(const float4*)(W + (size_t)(n0 + r) * D + i0 + c);
    tile[r][c+0] = vv.x; tile[r][c+1] = vv.y; tile[r][c+2] = vv.z; tile[r][c+3] = vv.w;
  }
  __syncthreads();
  #pragma unroll
  for (int p = 0; p < 4; ++p) {
    int ii = (t >> 4) + p * 16;
    int nn = (t & 15) * 4;
    ushort4v h, l;
    #pragma unroll
    for (int e = 0; e < 4; ++e) {
      float f = tile[nn + e][ii];
      unsigned int hb = f2bf_rn(f);
      float hf = __uint_as_float(hb << 16);
      h[e] = (u16t)hb;
      l[e] = (u16t)f2bf_rn(f - hf);
    }
    size_t idx = (size_t)(i0 + ii) * D + n0 + nn;
    *(ushort4v*)(oh + idx) = h;
    *(ushort4v*)(ol + idx) = l;
  }
}

// ---------------------------------------------------------------------------
// M[i][j] = sum_n Wq[n][i]Wk[n][j]; hi/lo 3-term.
// ---------------------------------------------------------------------------
__global__ __launch_bounds__(256) void m_kernel(
    const u16t* __restrict__ wqth, const u16t* __restrict__ wqtl,
    const u16t* __restrict__ wkth, const u16t* __restrict__ wktl,
    u16t* __restrict__ mh, u16t* __restrict__ ml)
{
  __shared__ __align__(16) u16t Mbuf[4][64 * BK];  // 0:Ah 1:Al 2:Bh 3:Bl

  const int tid  = threadIdx.x;
  const int lane = tid & 63;
  const int wv   = tid >> 6;
  const int i0   = blockIdx.x * 64;
  const int j0   = blockIdx.y * 64;

  floatx4 acc[2][2] = {};
  const int m0w = (wv & 1) * 32;
  const int n0w = (wv >> 1) * 32;
  const int srow = lane >> 2;
  const int scol = (lane & 3) * 8;

  for (int k0 = 0; k0 < D; k0 += BK) {
    __syncthreads();
    {
      const u16t* src = (wv == 0) ? wqth : (wv == 1) ? wqtl : (wv == 2) ? wkth : wktl;
      const int base  = (wv < 2) ? i0 : j0;
      #pragma unroll
      for (int sg = 0; sg < 4; ++sg) {
        int row = base + sg * 16 + srow;
        size_t g = (size_t)row * D + k0 + scol;
        __builtin_amdgcn_global_load_lds(
            (const __attribute__((address_space(1))) void*)(src + g),
            (__attribute__((address_space(3))) void*)(&Mbuf[wv][sg * 512]), 16, 0, 0);
      }
    }
    __syncthreads();
    short8 ah[2], al[2], bh[2], bl[2];
    #pragma unroll
    for (int t = 0; t < 2; ++t) {
      int ar = (m0w + t * 16 + (lane & 15)) * BK + (lane >> 4) * 8;
      int br = (n0w + t * 16 + (lane & 15)) * BK + (lane >> 4) * 8;
      ah[t] = *(const short8*)&Mbuf[0][ar];
      al[t] = *(const short8*)&Mbuf[1][ar];
      bh[t] = *(const short8*)&Mbuf[2][br];
      bl[t] = *(const short8*)&Mbuf[3][br];
    }
    #pragma unroll
    for (int mt = 0; mt < 2; ++mt)
      #pragma unroll
      for (int nt = 0; nt < 2; ++nt) {
        acc[mt][nt] = __builtin_amdgcn_mfma_f32_16x16x32_bf16(ah[mt], bh[nt], acc[mt][nt], 0, 0, 0);
        acc[mt][nt] = __builtin_amdgcn_mfma_f32_16x16x32_bf16(ah[mt], bl[nt], acc[mt][nt], 0, 0, 0);
        acc[mt][nt] = __builtin_amdgcn_mfma_f32_16x16x32_bf16(al[mt], bh[nt], acc[mt][nt], 0, 0, 0);
      }
  }
  #pragma unroll
  for (int mt = 0; mt < 2; ++mt)
    #pragma unroll
    for (int nt = 0; nt < 2; ++nt) {
      int j = j0 + n0w + nt * 16 + (lane & 15);
      int i = i0 + m0w + mt * 16 + (lane >> 4) * 4;
      #pragma unroll
      for (int r = 0; r < 4; ++r) {
        float f = acc[mt][nt][r];
        unsigned int hb = f2bf_rn(f);
        float hf = __uint_as_float(hb << 16);
        size_t idx = (size_t)(i + r) * D + j;
        mh[idx] = (u16t)hb;
        ml[idx] = (u16t)f2bf_rn(f - hf);
      }
    }
}

// ---------------------------------------------------------------------------
// Y[s][i] = sum_j x[s][j]*M[i][j]; hi/lo 3-term. BK=64 staged as two
// interleaved 32-halves ([h][row][col32], row stride 64B) -> half barriers.
// ---------------------------------------------------------------------------
__global__ __launch_bounds__(256) void y_kernel(
    const u16t* __restrict__ xhi, const u16t* __restrict__ xlo,
    const u16t* __restrict__ mhp, const u16t* __restrict__ mlp,
    u16t* __restrict__ yh, u16t* __restrict__ yl)
{
  __shared__ __align__(16) u16t Ah[2 * 128 * BK];
  __shared__ __align__(16) u16t Al[2 * 128 * BK];
  __shared__ __align__(16) u16t Bh[2 * 128 * BK];
  __shared__ __align__(16) u16t Bl[2 * 128 * BK];

  const int tid  = threadIdx.x;
  const int lane = tid & 63;
  const int wv   = tid >> 6;
  const int s0   = blockIdx.x * 128;
  const int i0   = blockIdx.y * 128;

  floatx4 acc[4][4] = {};
  const int m0w  = (wv & 1) * 64;
  const int n0w  = (wv >> 1) * 64;
  const int srow = lane >> 2;
  const int scol = (lane & 3) * 8;

  for (int k0 = 0; k0 < D; k0 += 64) {
    __syncthreads();
    #pragma unroll
    for (int h = 0; h < 2; ++h) {
      #pragma unroll
      for (int sg = 0; sg < 2; ++sg) {
        int seg  = wv * 2 + sg;
        int arow = s0 + seg * 16 + srow;
        int brow = i0 + seg * 16 + srow;
        size_t ga = (size_t)arow * D + k0 + h * 32 + scol;
        size_t gb = (size_t)brow * D + k0 + h * 32 + scol;
        int lb = h * 4096 + seg * 512;
        __builtin_amdgcn_global_load_lds(
            (const __attribute__((address_space(1))) void*)(xhi + ga),
            (__attribute__((address_space(3))) void*)(&Ah[lb]), 16, 0, 0);
        __builtin_amdgcn_global_load_lds(
            (const __attribute__((address_space(1))) void*)(xlo + ga),
            (__attribute__((address_space(3))) void*)(&Al[lb]), 16, 0, 0);
        __builtin_amdgcn_global_load_lds(
            (const __attribute__((address_space(1))) void*)(mhp + gb),
            (__attribute__((address_space(3))) void*)(&Bh[lb]), 16, 0, 0);
        __builtin_amdgcn_global_load_lds(
            (const __attribute__((address_space(1))) void*)(mlp + gb),
            (__attribute__((address_space(3))) void*)(&Bl[lb]), 16, 0, 0);
      }
    }
    __syncthreads();
    #pragma unroll
    for (int h = 0; h < 2; ++h) {
      short8 ah[4], al[4], bh[4], bl[4];
      #pragma unroll
      for (int t = 0; t < 4; ++t) {
        int ar = h * 4096 + (m0w + t * 16 + (lane & 15)) * BK + (lane >> 4) * 8;
        int br = h * 4096 + (n0w + t * 16 + (lane & 15)) * BK + (lane >> 4) * 8;
        ah[t] = *(const short8*)&Ah[ar];
        al[t] = *(const short8*)&Al[ar];
        bh[t] = *(const short8*)&Bh[br];
        bl[t] = *(const short8*)&Bl[br];
      }
      #pragma unroll
      for (int mt = 0; mt < 4; ++mt)
        #pragma unroll
        for (int nt = 0; nt < 4; ++nt) {
          acc[mt][nt] = __builtin_amdgcn_mfma_f32_16x16x32_bf16(ah[mt], bh[nt], acc[mt][nt], 0, 0, 0);
          acc[mt][nt] = __builtin_amdgcn_mfma_f32_16x16x32_bf16(ah[mt], bl[nt], acc[mt][nt], 0, 0, 0);
          acc[mt][nt] = __builtin_amdgcn_mfma_f32_16x16x32_bf16(al[mt], bh[nt], acc[mt][nt], 0, 0, 0);
        }
    }
  }
  #pragma unroll
  for (int mt = 0; mt < 4; ++mt)
    #pragma unroll
    for (int nt = 0; nt < 4; ++nt) {
      int i = i0 + n0w + nt * 16 + (lane & 15);
      int s = s0 + m0w + mt * 16 + (lane >> 4) * 4;
      #pragma unroll
      for (int r = 0; r < 4; ++r) {
        float f = acc[mt][nt][r];
        unsigned int hb = f2bf_rn(f);
        float hf = __uint_as_float(hb << 16);
        size_t idx = (size_t)(s + r) * D + i;
        yh[idx] = (u16t)hb;
        yl[idx] = (u16t)f2bf_rn(f - hf);
      }
    }
}

// ---------------------------------------------------------------------------
// Banded scores: band[t][j] = x_t.Y_s + a[t] + b[s] + c  (s = t0-128+j),
// hi/lo 3-term, BK=64 two-half staging. Window-masked (else 0).
// ---------------------------------------------------------------------------
__global__ __launch_bounds__(256) void scores_kernel(
    const u16t* __restrict__ xhi, const u16t* __restrict__ xlo,
    const u16t* __restrict__ yh, const u16t* __restrict__ yl,
    const float* __restrict__ a, const float* __restrict__ b,
    const float* __restrict__ cbuf, float* __restrict__ band)
{
  __shared__ __align__(16) u16t Ah[2 * 128 * BK];
  __shared__ __align__(16) u16t Al[2 * 128 * BK];
  __shared__ __align__(16) u16t Bh[2 * 128 * BK];
  __shared__ __align__(16) u16t Bl[2 * 128 * BK];

  const int tid  = threadIdx.x;
  const int lane = tid & 63;
  const int wv   = tid >> 6;
  const int t0   = blockIdx.x * 128;
  const int jt   = blockIdx.y;
  const int s_base = t0 - 128 + jt * 128;
  const float cval = cbuf[0];

  floatx4 acc[4][4] = {};
  const int m0w  = (wv & 1) * 64;
  const int n0w  = (wv >> 1) * 64;
  const int srow = lane >> 2;
  const int scol = (lane & 3) * 8;

  for (int k0 = 0; k0 < D; k0 += 64) {
    __syncthreads();
    #pragma unroll
    for (int h = 0; h < 2; ++h) {
      #pragma unroll
      for (int sg = 0; sg < 2; ++sg) {
        int seg  = wv * 2 + sg;
        int arow = t0 + seg * 16 + srow;
        int brow = s_base + seg * 16 + srow;
        brow = min(max(brow, 0), S - 1);
        size_t ga = (size_t)arow * D + k0 + h * 32 + scol;
        size_t gb = (size_t)brow * D + k0 + h * 32 + scol;
        int lb = h * 4096 + seg * 512;
        __builtin_amdgcn_global_load_lds(
            (const __attribute__((address_space(1))) void*)(xhi + ga),
            (__attribute__((address_space(3))) void*)(&Ah[lb]), 16, 0, 0);
        __builtin_amdgcn_global_load_lds(
            (const __attribute__((address_space(1))) void*)(xlo + ga),
            (__attribute__((address_space(3))) void*)(&Al[lb]), 16, 0, 0);
        __builtin_amdgcn_global_load_lds(
            (const __attribute__((address_space(1))) void*)(yh + gb),
            (__attribute__((address_space(3))) void*)(&Bh[lb]), 16, 0, 0);
        __builtin_amdgcn_global_load_lds(
            (const __attribute__((address_space(1))) void*)(yl + gb),
            (__attribute__((address_space(3))) void*)(&Bl[lb]), 16, 0, 0);
      }
    }
    __syncthreads();
    #pragma unroll
    for (int h = 0; h < 2; ++h) {
      short8 ah[4], al[4], bh[4], bl[4];
      #pragma unroll
      for (int t = 0; t < 4; ++t) {
        int ar = h * 4096 + (m0w + t * 16 + (lane & 15)) * BK + (lane >> 4) * 8;
        int br = h * 4096 + (n0w + t * 16 + (lane & 15)) * BK + (lane >> 4) * 8;
        ah[t] = *(const short8*)&Ah[ar];
        al[t] = *(const short8*)&Al[ar];
        bh[t] = *(const short8*)&Bh[br];
        bl[t] = *(const short8*)&Bl[br];
      }
      #pragma unroll
      for (int mt = 0; mt < 4; ++mt)
        #pragma unroll
        for (int nt = 0; nt < 4; ++nt) {
          acc[mt][nt] = __builtin_amdgcn_mfma_f32_16x16x32_bf16(ah[mt], bh[nt], acc[mt][nt], 0, 0, 0);
          acc[mt][nt] = __builtin_amdgcn_mfma_f32_16x16x32_bf16(ah[mt], bl[nt], acc[mt][nt], 0, 0, 0);
          acc[mt][nt] = __builtin_amdgcn_mfma_f32_16x16x32_bf16(al[mt], bh[nt], acc[mt][nt], 0, 0, 0);
        }
    }
  }
  #pragma unroll
  for (int mt = 0; mt < 4; ++mt)
    #pragma unroll
    for (int nt = 0; nt < 4; ++nt) {
      int n_loc = n0w + nt * 16 + (lane & 15);
      int s = s_base + n_loc;
      float bv = (s >= 0 && s < S) ? b[s] : 0.f;
      #pragma unroll
      for (int r = 0; r < 4; ++r) {
        int m_loc = m0w + mt * 16 + (lane >> 4) * 4 + r;
        int t = t0 + m_loc;
        bool inwin = (s >= t - WINDOW) && (s < t + WINDOW) && (s >= 0) && (s < S);
        float sv = inwin ? (acc[mt][nt][r] + a[t] + bv + cval) : 0.f;
        band[(size_t)t * BAND + jt * 128 + n_loc] = sv;
      }
    }
}

// ---------------------------------------------------------------------------
// Softmax over band; P = (e - e0)*dinv as bf16; e0d = e0*dinv.
// ---------------------------------------------------------------------------
__global__ __launch_bounds__(256) void softmax_kernel(
    const float* __restrict__ band, u16t* __restrict__ Pb, float* __restrict__ e0d)
{
  const int lane = threadIdx.x & 63;
  const int w    = threadIdx.x >> 6;
  const int t    = blockIdx.x * 4 + w;
  const float* row = band + (size_t)t * BAND;
  float v[6];
  float mx = 0.f;
  #pragma unroll
  for (int i = 0; i < 6; ++i) {
    v[i] = row[i * 64 + lane];
    mx = fmaxf(mx, v[i]);
  }
  mx = wave_max(mx);
  float e0 = __expf(-mx);
  float ss = 0.f;
  #pragma unroll
  for (int i = 0; i < 6; ++i) {
    v[i] = __expf(v[i] - mx);
    ss += v[i];
  }
  ss = wave_sum(ss);
  float dinv = 1.f / (ss + (float)(S - BAND) * e0);
  #pragma unroll
  for (int i = 0; i < 6; ++i)
    Pb[(size_t)t * BAND + i * 64 + lane] = (u16t)f2bf_rn((v[i] - e0) * dinv);
  if (lane == 0) e0d[t] = e0 * dinv;
}

// ---------------------------------------------------------------------------
// PV: out[t][d] = sum_j Pb[t][j]*x[origin+j][d] + e0d[t]*xsum[d]. BK=64.
// ---------------------------------------------------------------------------
__global__ __launch_bounds__(256) void pv_kernel(
    const u16t* __restrict__ Pb, const u16t* __restrict__ xT,
    const float* __restrict__ e0d, const float* __restrict__ xsum,
    float* __restrict__ out)
{
  __shared__ __align__(16) u16t Ab[2 * 128 * BK];
  __shared__ __align__(16) u16t Bb[2 * 128 * BK];

  const int tid  = threadIdx.x;
  const int lane = tid & 63;
  const int wv   = tid >> 6;
  const int t0   = blockIdx.x * 128;
  const int d0   = blockIdx.y * 128;
  const int origin = t0 - 128;

  floatx4 acc[4][4] = {};
  const int m0w  = (wv & 1) * 64;
  const int n0w  = (wv >> 1) * 64;
  const int srow = lane >> 2;
  const int scol = (lane & 3) * 8;

  for (int k0 = 0; k0 < BAND; k0 += 64) {
    __syncthreads();
    #pragma unroll
    for (int h = 0; h < 2; ++h) {
      #pragma unroll
      for (int sg = 0; sg < 2; ++sg) {
        int seg  = wv * 2 + sg;
        int arow = t0 + seg * 16 + srow;
        int brow = d0 + seg * 16 + srow;
        int s_g  = origin + k0 + h * 32 + scol;
        s_g = min(max(s_g, 0), S - 8);
        size_t ga = (size_t)arow * BAND + k0 + h * 32 + scol;
        size_t gb = (size_t)brow * S + s_g;
        int lb = h * 4096 + seg * 512;
        __builtin_amdgcn_global_load_lds(
            (const __attribute__((address_space(1))) void*)(Pb + ga),
            (__attribute__((address_space(3))) void*)(&Ab[lb]), 16, 0, 0);
        __builtin_amdgcn_global_load_lds(
            (const __attribute__((address_space(1))) void*)(xT + gb),
            (__attribute__((address_space(3))) void*)(&Bb[lb]), 16, 0, 0);
      }
    }
    __syncthreads();
    #pragma unroll
    for (int h = 0; h < 2; ++h) {
      short8 af[4], bf[4];
      #pragma unroll
      for (int t = 0; t < 4; ++t) {
        int ar = h * 4096 + (m0w + t * 16 + (lane & 15)) * BK + (lane >> 4) * 8;
        int br = h * 4096 + (n0w + t * 16 + (lane & 15)) * BK + (lane >> 4) * 8;
        af[t] = *(const short8*)&Ab[ar];
        bf[t] = *(const short8*)&Bb[br];
      }
      #pragma unroll
      for (int mt = 0; mt < 4; ++mt)
        #pragma unroll
        for (int nt = 0; nt < 4; ++nt)
          acc[mt][nt] = __builtin_amdgcn_mfma_f32_16x16x32_bf16(af[mt], bf[nt], acc[mt][nt], 0, 0, 0);
    }
  }
  #pragma unroll
  for (int mt = 0; mt < 4; ++mt)
    #pragma unroll
    for (int nt = 0; nt < 4; ++nt) {
      int n_g = d0 + n0w + nt * 16 + (lane & 15);
      float xs = xsum[n_g];
      #pragma unroll
      for (int r = 0; r < 4; ++r) {
        int m_g = t0 + m0w + mt * 16 + (lane >> 4) * 4 + r;
        out[(size_t)m_g * D + n_g] = acc[mt][nt][r] + e0d[m_g] * xs;
      }
    }
}

// ---------------------------------------------------------------------------
// Fallback path (round-3 verified): fp32 proj + VALU attn
// ---------------------------------------------------------------------------
__global__ __launch_bounds__(256) void proj_kernel(
    const float* __restrict__ x, const float* __restrict__ Wq,
    const float* __restrict__ bqv, const float* __restrict__ Wk,
    const float* __restrict__ bkv, float* __restrict__ qout,
    float* __restrict__ kout)
{
  __shared__ __align__(16) float xs[BK][PAD];
  __shared__ __align__(16) float wqs[BK][PAD];
  __shared__ __align__(16) float wks[BK][PAD];
  const int tid = threadIdx.x;
  const int tx = tid & 15, ty = tid >> 4;
  const int t0 = blockIdx.x * 64, i0 = blockIdx.y * 64;
  float accq[4][4] = {}, acck[4][4] = {};
  const int lrow0 = tid >> 3, lc4 = (tid & 7) * 4;
  for (int k0 = 0; k0 < D; k0 += BK) {
    __syncthreads();
    #pragma unroll
    for (int p = 0; p < 2; ++p) {
      int row = lrow0 + p * 32;
      float4 a = *(const float4*)(x  + (size_t)(t0 + row) * D + k0 + lc4);
      float4 b = *(const float4*)(Wq + (size_t)(i0 + row) * D + k0 + lc4);
      float4 c = *(const float4*)(Wk + (size_t)(i0 + row) * D + k0 + lc4);
      xs [lc4+0][row]=a.x; xs [lc4+1][row]=a.y; xs [lc4+2][row]=a.z; xs [lc4+3][row]=a.w;
      wqs[lc4+0][row]=b.x; wqs[lc4+1][row]=b.y; wqs[lc4+2][row]=b.z; wqs[lc4+3][row]=b.w;
      wks[lc4+0][row]=c.x; wks[lc4+1][row]=c.y; wks[lc4+2][row]=c.z; wks[lc4+3][row]=c.w;
    }
    __syncthreads();
    #pragma unroll
    for (int kk = 0; kk < BK; ++kk) {
      float4 av = *(const float4*)&xs [kk][ty*4];
      float4 bv = *(const float4*)&wqs[kk][tx*4];
      float4 cv = *(const float4*)&wks[kk][tx*4];
      float a[4] = {av.x, av.y, av.z, av.w};
      float b[4] = {bv.x, bv.y, bv.z, bv.w};
      float c[4] = {cv.x, cv.y, cv.z, cv.w};
      #pragma unroll
      for (int r = 0; r < 4; ++r)
        #pragma unroll
        for (int cc = 0; cc < 4; ++cc) {
          accq[r][cc] = fmaf(a[r], b[cc], accq[r][cc]);
          acck[r][cc] = fmaf(a[r], c[cc], acck[r][cc]);
        }
    }
  }
  float4 bq4 = *(const float4*)(bqv + i0 + tx*4);
  float4 bk4 = *(const float4*)(bkv + i0 + tx*4);
  #pragma unroll
  for (int r = 0; r < 4; ++r) {
    int trow = t0 + ty*4 + r;
    float4 oq = { accq[r][0]+bq4.x, accq[r][1]+bq4.y, accq[r][2]+bq4.z, accq[r][3]+bq4.w };
    float4 ok = { acck[r][0]+bk4.x, acck[r][1]+bk4.y, acck[r][2]+bk4.z, acck[r][3]+bk4.w };
    *(float4*)(qout + (size_t)trow * D + i0 + tx*4) = oq;
    *(float4*)(kout + (size_t)trow * D + i0 + tx*4) = ok;
  }
}

__global__ __launch_bounds__(256) void colsum_kernel(const float* __restrict__ x,
                                                     float* __restrict__ xsum)
{
  int d = blockIdx.x * 256 + threadIdx.x;
  int tbase = blockIdx.y * 256;
  float s = 0.f;
  for (int t = 0; t < 256; ++t) s += x[(size_t)(tbase + t) * D + d];
  atomicAdd(&xsum[d], s);
}

__global__ __launch_bounds__(256) void attn_kernel(
    const float* __restrict__ x, const float* __restrict__ q,
    const float* __restrict__ kmat, const float* __restrict__ xsum,
    float* __restrict__ out)
{
  __shared__ __align__(16) float scl[TQ][UMAX];
  __shared__ float e0s[TQ], dinv[TQ];
  const int tid = threadIdx.x, lane = tid & 63, wv = tid >> 6;
  const int t0 = blockIdx.x * TQ;
  const int lo_u = max(0, t0 - WINDOW);
  const int hi_u = min(S, t0 + TQ - 1 + WINDOW);
  const int ucnt = hi_u - lo_u;
  for (int i = tid; i < TQ * UMAX; i += 256) (&scl[0][0])[i] = 0.f;
  __syncthreads();
  {
    const int tiB = wv * 4;
    float4 qf[4][4];
    #pragma unroll
    for (int g = 0; g < 4; ++g) {
      int t = t0 + tiB + g;
      #pragma unroll
      for (int j = 0; j < 4; ++j)
        qf[g][j] = *(const float4*)(q + (size_t)t * D + lane*4 + j*256);
    }
    const int wlo = max(0, t0 + tiB - WINDOW);
    const int whi = min(S, t0 + tiB + 3 + WINDOW);
    for (int s = wlo; s < whi; ++s) {
      float4 kf[4];
      #pragma unroll
      for (int j = 0; j < 4; ++j)
        kf[j] = *(const float4*)(kmat + (size_t)s * D + lane*4 + j*256);
      float acc[4];
      #pragma unroll
      for (int g = 0; g < 4; ++g) {
        float v = 0.f;
        #pragma unroll
        for (int j = 0; j < 4; ++j) {
          v = fmaf(qf[g][j].x, kf[j].x, v);
          v = fmaf(qf[g][j].y, kf[j].y, v);
          v = fmaf(qf[g][j].z, kf[j].z, v);
          v = fmaf(qf[g][j].w, kf[j].w, v);
        }
        acc[g] = v;
      }
      #pragma unroll
      for (int g = 0; g < 4; ++g) {
        float tot = wave_sum(acc[g]);
        int t = t0 + tiB + g;
        if (lane == 0 && s >= t - WINDOW && s < t + WINDOW)
          scl[tiB + g][s - lo_u] = tot;
      }
    }
  }
  __syncthreads();
  #pragma unroll
  for (int g = 0; g < 4; ++g) {
    int ti = wv * 4 + g;
    int t = t0 + ti;
    int lo = max(0, t - WINDOW), hi = min(S, t + WINDOW);
    int cnt = hi - lo, off = lo - lo_u;
    float m = 0.f;
    for (int i = lane; i < cnt; i += 64) m = fmaxf(m, scl[ti][off + i]);
    m = wave_max(m);
    float e0 = __expf(-m);
    float ssum = 0.f;
    for (int i = lane; i < cnt; i += 64) {
      float e = __expf(scl[ti][off + i] - m);
      ssum += e;
      scl[ti][off + i] = e - e0;
    }
    ssum = wave_sum(ssum);
    if (lane == 0) {
      dinv[ti] = 1.f / (ssum + (float)(S - cnt) * e0);
      e0s[ti] = e0;
    }
  }
  __syncthreads();
  {
    const int c4 = tid * 4;
    float4 acc[TQ];
    #pragma unroll
    for (int ti = 0; ti < TQ; ++ti) acc[ti] = make_float4(0.f, 0.f, 0.f, 0.f);
    for (int su = 0; su < ucnt; su += 4) {
      float4 xr[4];
      #pragma unroll
      for (int u = 0; u < 4; ++u)
        xr[u] = *(const float4*)(x + (size_t)(lo_u + su + u) * D + c4);
      #pragma unroll
      for (int ti = 0; ti < TQ; ++ti) {
        float4 w4 = *(const float4*)&scl[ti][su];
        float wvv[4] = {w4.x, w4.y, w4.z, w4.w};
        #pragma unroll
        for (int u = 0; u < 4; ++u) {
          acc[ti].x = fmaf(wvv[u], xr[u].x, acc[ti].x);
          acc[ti].y = fmaf(wvv[u], xr[u].y, acc[ti].y);
          acc[ti].z = fmaf(wvv[u], xr[u].z, acc[ti].z);
          acc[ti].w = fmaf(wvv[u], xr[u].w, acc[ti].w);
        }
      }
    }
    float4 xsv = *(const float4*)(xsum + c4);
    #pragma unroll
    for (int ti = 0; ti < TQ; ++ti) {
      float e0 = e0s[ti], di = dinv[ti];
      float4 o;
      o.x = (acc[ti].x + e0 * xsv.x) * di;
      o.y = (acc[ti].y + e0 * xsv.y) * di;
      o.z = (acc[ti].z + e0 * xsv.z) * di;
      o.w = (acc[ti].w + e0 * xsv.w) * di;
      *(float4*)(out + (size_t)(t0 + ti) * D + c4) = o;
    }
  }
}

extern "C" void kernel_launch(void* const* d_in, const int* in_sizes, int n_in,
                              void* d_out, int out_size, void* d_ws, size_t ws_size,
                              hipStream_t stream) {
  const float* x  = (const float*)d_in[0];
  const float* Wq = (const float*)d_in[1];
  const float* bq = (const float*)d_in[2];
  const float* Wk = (const float*)d_in[3];
  const float* bk = (const float*)d_in[4];
  float* outp = (float*)d_out;

  const size_t SD = (size_t)S * D;
  const size_t DD = (size_t)D * D;

  // fp32 scalar region (zeroed by one memset)
  float* xsum = (float*)d_ws;            // D
  float* u    = xsum + D;                // D
  float* v    = u + D;                   // D
  float* a    = v + D;                   // S
  float* b    = a + S;                   // S
  float* cbuf = b + S;                   // 16
  size_t zero_bytes = (size_t)(3 * D + 2 * S + 16) * sizeof(float);

  u16t* xhi  = (u16t*)(cbuf + 16);
  u16t* xlo  = xhi + SD;
  u16t* xT   = xlo + SD;
  u16t* wqth = xT + SD;
  u16t* wqtl = wqth + DD;
  u16t* wkth = wqtl + DD;
  u16t* wktl = wkth + DD;
  u16t* mh   = wktl + DD;
  u16t* ml   = mh + DD;
  u16t* yh   = ml + DD;
  u16t* yl   = yh + SD;
  float* band = (float*)(yl + SD);                // S*BAND f32
  u16t*  Pb   = (u16t*)(band + (size_t)S * BAND); // S*BAND u16
  float* e0d  = (float*)(Pb + (size_t)S * BAND);  // S f32
  size_t needed = (size_t)((char*)(e0d + S) - (char*)d_ws);

  if (ws_size >= needed) {
    (void)hipMemsetAsync(d_ws, 0, zero_bytes, stream);
    uv_kernel<<<dim3(D / 256, 8), 256, 0, stream>>>(Wq, Wk, bq, bk, u, v, cbuf);
    prep_kernel<<<dim3(S / 64, D / 64), 256, 0, stream>>>(x, u, v, xhi, xlo, xT, xsum, a, b);
    transposeW_kernel<<<dim3(D / 64, D / 64, 2), 256, 0, stream>>>(Wq, Wk, wqth, wqtl, wkth, wktl);
    m_kernel<<<dim3(D / 64, D / 64), 256, 0, stream>>>(wqth, wqtl, wkth, wktl, mh, ml);
    y_kernel<<<dim3(S / 128, D / 128), 256, 0, stream>>>(xhi, xlo, mh, ml, yh, yl);
    scores_kernel<<<dim3(S / 128, 3), 256, 0, stream>>>(xhi, xlo, yh, yl, a, b, cbuf, band);
    softmax_kernel<<<S / 4, 256, 0, stream>>>(band, Pb, e0d);
    pv_kernel<<<dim3(S / 128, D / 128), 256, 0, stream>>>(Pb, xT, e0d, xsum, outp);
  } else {
    float* xs2  = (float*)d_ws;
    float* q    = xs2 + D;
    float* kbuf = q + SD;
    (void)hipMemsetAsync(xs2, 0, D * sizeof(float), stream);
    colsum_kernel<<<dim3(D / 256, S / 256), 256, 0, stream>>>(x, xs2);
    proj_kernel<<<dim3(S / 64, D / 64), 256, 0, stream>>>(x, Wq, bq, Wk, bk, q, kbuf);
    attn_kernel<<<S / TQ, 256, 0, stream>>>(x, q, kbuf, xs2, outp);
  }
}